// Round 13
// baseline (1335.989 us; speedup 1.0000x reference)
//
#include <hip/hip_runtime.h>

#define BATCH 32
#define ATOMS 128
#define CCH 3
#define XH 57
#define XW 57
#define OHH 64
#define OWW 64
#define KSEL 2000
#define PIX (XH*XW)            // 3249
#define NPS (ATOMS*PIX)        // 415872 per-sample X elements
#define NTOT (BATCH*NPS)       // 13307904
#define RPS (CCH*OHH*OWW)      // 12288 per-sample R elements
#define RTOT (BATCH*RPS)       // 393216
#define CANDCAP 32768
#define NW 24576               // weight elements 128*3*8*8
#define ZWORDS (32*2048 + 32*1024)   // g1+g2 words

typedef double f64x4 __attribute__((ext_vector_type(4)));
typedef unsigned long long u64;

// ---------------------------------------------------------------------------
// Prep (once): weight f64 layouts, Rd = -Y init, zero g1/g2/candcnt/nzcnt.
// ---------------------------------------------------------------------------
__global__ __launch_bounds__(256) void prep_k(const float* __restrict__ Wg,
    double* __restrict__ WDd, double* __restrict__ Wt2d,
    const float* __restrict__ Y, double* __restrict__ Rd,
    unsigned* __restrict__ zbuf) {
  int e = blockIdx.x * 256 + threadIdx.x;
  if (e < NW) {
    {
      int kw = e & 7; int t = e >> 3; int c = t % 3; t /= 3; int kh = t & 7; int a = t >> 3;
      WDd[e] = (double)Wg[(a*3 + c)*64 + kh*8 + kw];
    }
    {
      int a = e & 127; int t = e >> 7; int j = t & 7; int i = (t >> 3) & 7; int c = t >> 6;
      Wt2d[e] = (double)Wg[(a*3 + c)*64 + j*8 + i];
    }
  }
  if (e < RTOT) Rd[e] = -(double)Y[e];
  if (e < ZWORDS + 64) zbuf[e] = 0;
}

// ---------------------------------------------------------------------------
// MFMA f64 layout probe + decode (one wave, one-time). NO layout assumptions:
// 64 probes A=e_i, B[lane]=lane+1 (exact ints); row classes from support
// equality, k classes from observed-B-set equality, n classes from B-4-set
// equality. Self-test with exact integer GEMM sets ok flag; convDtMM falls
// back to a VALU path if ok==0. Tables: a_m,a_k,b_k,b_n[64], d_m,d_n[256].
// ---------------------------------------------------------------------------
__global__ __launch_bounds__(64) void mfprobe_k(double* __restrict__ prg,
                                                int* __restrict__ tabs) {
  int lane = threadIdx.x;
  // phase 1: probes -> global (cross-lane visibility via __syncthreads)
  for (int i = 0; i < 64; ++i) {
    double aval = (lane == i) ? 1.0 : 0.0;
    double bval = (double)(lane + 1);
    f64x4 acc = {0.0, 0.0, 0.0, 0.0};
    acc = __builtin_amdgcn_mfma_f64_16x16x4f64(aval, bval, acc, 0, 0, 0);
#pragma unroll
    for (int r = 0; r < 4; ++r) prg[(i * 64 + lane) * 4 + r] = acc[r];
  }
  __syncthreads();
  __shared__ u64 ssupp[64][4];
  __shared__ u64 sbm[64];
  __shared__ int mrow[64], kcls[64];
  __shared__ int reps[16];
  __shared__ int classmem[16][4];
  __shared__ u64 colsets[16];
  __shared__ int posrow[256];
  __shared__ int pn[256];
  __shared__ int okflag;
  // phase 2: thread `lane` builds masks for probe i=lane
  {
    u64 m[4] = {0, 0, 0, 0}, bm = 0;
    for (int p2 = 0; p2 < 256; ++p2) {
      double v = prg[lane * 256 + p2];
      if (v != 0.0) {
        int b = (int)v - 1;
        if (b >= 0 && b < 64) bm |= (1ull << b);
        m[p2 >> 6] |= (1ull << (p2 & 63));
      }
    }
#pragma unroll
    for (int q = 0; q < 4; ++q) ssupp[lane][q] = m[q];
    sbm[lane] = bm;
  }
  __syncthreads();
  if (lane == 0) {
    int nrows = 0, nks = 0;
    u64 krep[4];
    for (int i = 0; i < 64; ++i) {
      int c = -1;
      for (int q = 0; q < nrows && q < 16; ++q) {
        int rp = reps[q];
        if (ssupp[i][0] == ssupp[rp][0] && ssupp[i][1] == ssupp[rp][1] &&
            ssupp[i][2] == ssupp[rp][2] && ssupp[i][3] == ssupp[rp][3]) { c = q; break; }
      }
      if (c < 0) { c = nrows; if (nrows < 16) reps[nrows] = i; nrows++; }
      mrow[i] = c < 16 ? c : 0;
      int kc = -1;
      for (int q = 0; q < nks && q < 4; ++q) if (sbm[i] == krep[q]) { kc = q; break; }
      if (kc < 0) { kc = nks; if (nks < 4) krep[nks] = sbm[i]; nks++; }
      kcls[i] = kc < 4 ? kc : 0;
    }
    for (int c = 0; c < 16; ++c)
      for (int q = 0; q < 4; ++q) classmem[c][q] = -1;
    for (int i = 0; i < 64; ++i) classmem[mrow[i]][kcls[i]] = i;
    for (int p2 = 0; p2 < 256; ++p2) posrow[p2] = -1;
    for (int c = 0; c < nrows && c < 16; ++c) {
      int rp = reps[c];
      for (int p2 = 0; p2 < 256; ++p2)
        if ((ssupp[rp][p2 >> 6] >> (p2 & 63)) & 1) posrow[p2] = c;
    }
    int nc = 0;
    for (int p2 = 0; p2 < 256; ++p2) {
      if (posrow[p2] == 0) {
        u64 cs = 0;
        for (int q = 0; q < 4; ++q) {
          int i = classmem[0][q];
          if (i >= 0) {
            double v = prg[i * 256 + p2];
            if (v != 0.0) cs |= (1ull << ((int)v - 1));
          }
        }
        if (nc < 16) colsets[nc] = cs;
        nc++;
      }
    }
    okflag = (nrows == 16 && nks == 4 && nc == 16) ? 1 : 0;
  }
  __syncthreads();
  // phase 3: per-position n (4 positions per lane)
  for (int r = 0; r < 4; ++r) {
    int p2 = lane * 4 + r;
    int c = posrow[p2];
    int n = -1;
    if (c >= 0) {
      u64 cs = 0;
      for (int q = 0; q < 4; ++q) {
        int i = classmem[c][q];
        if (i >= 0) {
          double v = prg[i * 256 + p2];
          if (v != 0.0) cs |= (1ull << ((int)v - 1));
        }
      }
      for (int q = 0; q < 16; ++q) if (colsets[q] == cs) { n = q; break; }
    }
    pn[p2] = n;
  }
  __syncthreads();
  // phase 4: B tables (lane = b)
  int bk = -1, bn = -1;
  for (int i = 0; i < 64; ++i)
    if ((sbm[i] >> lane) & 1) { bk = kcls[i]; break; }
  for (int q = 0; q < 16; ++q)
    if ((colsets[q] >> lane) & 1) { bn = q; break; }
  // phase 5: self-test, exact integers (order-independent)
  {
    double aval = (double)(mrow[lane] * 4 + kcls[lane] + 1);
    double bval = (bk >= 0 && bn >= 0) ? (double)(bk * 16 + bn + 3) : 0.0;
    f64x4 acc = {0.0, 0.0, 0.0, 0.0};
    acc = __builtin_amdgcn_mfma_f64_16x16x4f64(aval, bval, acc, 0, 0, 0);
    bool ok = (bk >= 0 && bn >= 0);
#pragma unroll
    for (int r = 0; r < 4; ++r) {
      int p2 = lane * 4 + r;
      int m = posrow[p2], n = pn[p2];
      if (m < 0 || n < 0) { ok = false; continue; }
      double ref = 0.0;
      for (int k = 0; k < 4; ++k)
        ref += (double)(m * 4 + k + 1) * (double)(k * 16 + n + 3);
      if (acc[r] != ref) ok = false;
    }
    u64 vote = __ballot(ok);
    if (lane == 0 && vote != ~0ull) okflag = 0;
  }
  __syncthreads();
  // phase 6: write tables
  tabs[lane]       = mrow[lane];
  tabs[64 + lane]  = kcls[lane];
  tabs[128 + lane] = bk;
  tabs[192 + lane] = bn;
#pragma unroll
  for (int r = 0; r < 4; ++r) {
    tabs[256 + lane * 4 + r] = posrow[lane * 4 + r];
    tabs[512 + lane * 4 + r] = pn[lane * 4 + r];
  }
  if (lane == 0) tabs[768] = okflag;
}

// ---------------------------------------------------------------------------
// DENSE R += D(X) (iteration 0 only). Verified r11 version, unchanged.
// ---------------------------------------------------------------------------
__global__ __launch_bounds__(256) void convD_k(const float* __restrict__ X,
    const double* __restrict__ WDd, double* __restrict__ Rd) {
  __shared__ double Xs[4][11][72];            // 25344 B
  int p = blockIdx.x;
  int lg = (p & 7) * 256 + (p >> 3);          // bijective: 2048 = 8*256
  int b = lg >> 6; int rem = lg & 63;
  int band = rem >> 2, quarter = rem & 3;
  int row0 = band * 4;
  int a_base = quarter * 32;
  int tid = threadIdx.x;
  int ox = tid & 63;
  int wv = __builtin_amdgcn_readfirstlane(tid >> 6);
  const float* Xb = X + (size_t)b * NPS;

  double acc[4][3];
#pragma unroll
  for (int ty = 0; ty < 4; ++ty)
#pragma unroll
    for (int c = 0; c < 3; ++c) acc[ty][c] = 0.0;

  for (int ch = 0; ch < 8; ++ch) {
    __syncthreads();
    for (int e = tid; e < 4 * 11 * 72; e += 256) {
      int ai = e / 792; int rem2 = e - ai * 792;
      int r = rem2 / 72; int ss = rem2 - r * 72;
      int gy = row0 - 7 + r;
      int xcol = ss - 7;
      int a = a_base + ch * 4 + ai;
      float v = 0.0f;
      if ((unsigned)xcol < (unsigned)XW && (unsigned)gy < (unsigned)XH)
        v = Xb[a * PIX + gy * XW + xcol];
      Xs[ai][r][ss] = (double)v;
    }
    __syncthreads();
    {
      int a = a_base + ch * 4 + wv;
      const double* Wa = WDd + a * 192;       // [kh][c][kw]
#pragma unroll
      for (int r = 0; r < 11; ++r) {
        int gy = row0 - 7 + r;
        if ((unsigned)gy >= (unsigned)XH) continue;   // uniform
        double xd[8];
#pragma unroll
        for (int t = 0; t < 8; ++t) xd[t] = Xs[wv][r][ox + t];
#pragma unroll
        for (int ty = 0; ty < 4; ++ty) {
          int kh = ty + 7 - r;
          if ((unsigned)kh < 8u) {
            const double* Wk = Wa + kh * 24;
#pragma unroll
            for (int kw = 0; kw < 8; ++kw) {
              acc[ty][0] = fma(xd[7 - kw], Wk[kw],      acc[ty][0]);
              acc[ty][1] = fma(xd[7 - kw], Wk[8 + kw],  acc[ty][1]);
              acc[ty][2] = fma(xd[7 - kw], Wk[16 + kw], acc[ty][2]);
            }
          }
        }
      }
    }
  }
#pragma unroll
  for (int ty = 0; ty < 4; ++ty) {
    int oy = row0 + ty;
#pragma unroll
    for (int c = 0; c < 3; ++c)
      atomicAdd(&Rd[((size_t)(b * CCH + c) << 12) + (oy << 6) + ox], acc[ty][c]);
  }
}

// ---------------------------------------------------------------------------
// SPARSE R = D(X) - Y (iterations 1,2). Verified, unchanged.
// ---------------------------------------------------------------------------
__global__ __launch_bounds__(256) void convD_sparse_k(const float* __restrict__ Wg,
    const int* __restrict__ nzidx, const float* __restrict__ nzval,
    const float* __restrict__ Y, float* __restrict__ R) {
  __shared__ double accd[512];       // [rr][ox]
  __shared__ float Wf[8192];         // [a][kh][kw] for this c
  __shared__ int   li[KSEL];
  __shared__ float lv[KSEL];
  int p = blockIdx.x;
  int lg = (p & 7) * 96 + (p >> 3);  // bijective: 768 = 8*96
  int s = lg / 24; int r = lg % 24; int c = r >> 3; int band = r & 7;
  int row0 = band * 8;
  int tid = threadIdx.x;
  for (int e = tid; e < 512; e += 256) accd[e] = 0.0;
  for (int e = tid; e < 8192; e += 256) {
    int a = e >> 6, k2 = e & 63;
    Wf[e] = Wg[(a * 3 + c) * 64 + k2];
  }
  for (int e = tid; e < KSEL; e += 256) {
    li[e] = nzidx[s * KSEL + e];
    lv[e] = nzval[s * KSEL + e];
  }
  __syncthreads();
  int slot = tid >> 3, kw = tid & 7;
  for (int e = slot; e < KSEL; e += 32) {
    int idx = li[e];
    int a = (int)((unsigned)idx / 3249u);
    int pp = idx - a * 3249;
    int y = (int)((unsigned)pp / 57u);
    int x = pp - y * 57;
    int dy = y - row0;
    if (dy < -7 || dy > 7) continue;
    double val = (double)lv[e];
    const float* wp = Wf + (a << 6) + kw;
#pragma unroll
    for (int kh = 0; kh < 8; ++kh) {
      int rr = dy + kh;
      if ((unsigned)rr < 8u)
        __hip_atomic_fetch_add(&accd[(rr << 6) + x + kw],
                               val * (double)wp[kh << 3],
                               __ATOMIC_RELAXED, __HIP_MEMORY_SCOPE_WORKGROUP);
    }
  }
  __syncthreads();
  const float* Yb = Y + (((size_t)(s * CCH + c)) << 12) + (row0 << 6);
  float* Rb = R + (((size_t)(s * CCH + c)) << 12) + (row0 << 6);
  for (int e = tid; e < 512; e += 256)
    Rb[e] = (float)(accd[e] - (double)Yb[e]);
}

// ---------------------------------------------------------------------------
// HT = Xprev - Dt(R) via probed f64 MFMA, fused L1 hist. GEMM per sample:
// M=128 (8 tiles), K=192, N=pixels. Block=(b,y); 4 waves = 4 x-chunks of 16.
// R rows y..y+7 staged f64 in LDS; A streamed from L2-hot Wt2d[k][a].
// All fragment indexing from probe tables (arbitrary-but-consistent labels).
// Falls back to VALU path if probe self-test failed (ok==0).
// ---------------------------------------------------------------------------
template <typename TR>
__global__ __launch_bounds__(256) void convDtMM_k(const TR* __restrict__ R,
    const double* __restrict__ Wt2d, const float* __restrict__ Xprev,
    float* __restrict__ HT, unsigned* __restrict__ g1,
    const int* __restrict__ tabs) {
  __shared__ double Rl[3][8][72];     // 13824 B
  __shared__ unsigned hh[1024];       // packed 2 u16 bins per word
  int p = blockIdx.x;
  int lg = (p & 7) * 228 + (p >> 3);  // bijective: 1824 = 8*228
  int b = lg / 57;
  int y = lg - b * 57;
  int tid = threadIdx.x;
  int lane = tid & 63;
  int wv = tid >> 6;
  int x0 = wv * 16;
  for (int e = tid; e < 1024; e += 256) hh[e] = 0;
  for (int e = tid; e < 3 * 8 * 72; e += 256) {
    int c = e / (8 * 72); int r2 = e - c * (8 * 72);
    int rr = r2 / 72; int cc = r2 - rr * 72;
    double v = 0.0;
    if (cc < OWW)
      v = (double)R[((size_t)(b * CCH + c) << 12) + ((y + rr) << 6) + cc];
    Rl[c][rr][cc] = v;
  }
  int am = tabs[lane], ak = tabs[64 + lane];
  int bk = tabs[128 + lane], bn = tabs[192 + lane];
  int dm[4], dn[4];
#pragma unroll
  for (int r = 0; r < 4; ++r) {
    dm[r] = tabs[256 + lane * 4 + r];
    dn[r] = tabs[512 + lane * 4 + r];
  }
  int ok = tabs[768];
  __syncthreads();

  if (ok) {
    f64x4 acc[8];
#pragma unroll
    for (int m = 0; m < 8; ++m) acc[m] = (f64x4){0.0, 0.0, 0.0, 0.0};
    const double* Wa = Wt2d + (size_t)ak * 128 + am;
    int bcol = x0 + bn;
#pragma unroll 4
    for (int step = 0; step < 48; ++step) {
      int kg = step * 4 + bk;
      int c = kg >> 6, i = (kg >> 3) & 7, j = kg & 7;
      double bval = Rl[c][i][bcol + j];
      const double* wp = Wa + (size_t)step * 512;    // step*4 k-rows * 128
#pragma unroll
      for (int m = 0; m < 8; ++m)
        acc[m] = __builtin_amdgcn_mfma_f64_16x16x4f64(wp[m * 16], bval,
                                                      acc[m], 0, 0, 0);
    }
    int pixbase = y * XW;
#pragma unroll
    for (int m = 0; m < 8; ++m) {
#pragma unroll
      for (int r = 0; r < 4; ++r) {
        int x = x0 + dn[r];
        if (x < XW) {
          int a = m * 16 + dm[r];
          size_t xo = ((size_t)(b * ATOMS + a)) * PIX + pixbase + x;
          float fv = (float)((double)Xprev[xo] - acc[m][r]);
          HT[xo] = fv;
          unsigned u = __float_as_uint(fv) & 0x7fffffffu;
          unsigned bin = u >> 20;
          atomicAdd(&hh[bin >> 1], 1u << ((bin & 1) << 4));
        }
      }
    }
  } else {
    // correct (slower) VALU fallback — only if probe self-test failed
    for (int idx = tid; idx < 128 * 64; idx += 256) {
      int a = idx >> 6, x = idx & 63;
      if (x >= XW) continue;
      double acc = 0.0;
      for (int kg = 0; kg < 192; ++kg) {
        int c = kg >> 6, i = (kg >> 3) & 7, j = kg & 7;
        acc = fma(Rl[c][i][x + j], Wt2d[(size_t)kg * 128 + a], acc);
      }
      size_t xo = ((size_t)(b * ATOMS + a)) * PIX + y * XW + x;
      float fv = (float)((double)Xprev[xo] - acc);
      HT[xo] = fv;
      unsigned u = __float_as_uint(fv) & 0x7fffffffu;
      unsigned bin = u >> 20;
      atomicAdd(&hh[bin >> 1], 1u << ((bin & 1) << 4));
    }
  }
  __syncthreads();
  unsigned* gp = g1 + (size_t)b * 2048;
  for (int e = tid; e < 1024; e += 256) {
    unsigned v = hh[e];
    unsigned lo = v & 0xffffu, hi = v >> 16;
    if (lo) atomicAdd(&gp[2 * e], lo);
    if (hi) atomicAdd(&gp[2 * e + 1], hi);
  }
}

// ---------------------------------------------------------------------------
// histwrite_k: one scan classifies every element vs b1 (certainly-kept /
// certainly-zero / uncertain), writes Xout, gathers candidates + L2 hist,
// emits certain-keeps to nz list. Verified r12, unchanged.
// ---------------------------------------------------------------------------
__global__ __launch_bounds__(256) void histwrite_k(const float* __restrict__ HT,
    const unsigned* __restrict__ g1, unsigned* __restrict__ g2,
    int* __restrict__ cand, int* __restrict__ candcnt,
    float* __restrict__ Xo, int* __restrict__ nzidx, float* __restrict__ nzval,
    int* __restrict__ nzcnt, int emit) {
  __shared__ unsigned h[1024];
  __shared__ unsigned part[256];
  __shared__ int lidx[4096];
  __shared__ int kidx[2048];
  __shared__ float kval[2048];
  __shared__ int lcnt, lbase, kcnt, kbase, b1_sh;
  int tid = threadIdx.x;
  int s = blockIdx.x >> 5;
  int chunk = blockIdx.x & 31;
  const unsigned* hg1 = g1 + (size_t)s * 2048;
  unsigned psum = 0;
#pragma unroll
  for (int e = 0; e < 8; ++e) psum += hg1[tid * 8 + e];
  part[tid] = psum;
  for (int e = tid; e < 1024; e += 256) h[e] = 0;
  if (tid == 0) { lcnt = 0; kcnt = 0; }
  __syncthreads();
  if (tid == 0) {
    int Kv = KSEL;
    unsigned cumBefore = 0;
    int bsel = 0;
    for (int q = 255; q >= 0; --q) {
      unsigned ps = part[q];
      if ((int)(cumBefore + ps) >= Kv) {
        for (int e = q * 8 + 7;; --e) {
          unsigned c2 = cumBefore + hg1[e];
          if ((int)c2 >= Kv) { bsel = e; break; }
          cumBefore = c2;
        }
        break;
      }
      cumBefore += ps;
    }
    b1_sh = bsel;
  }
  __syncthreads();
  unsigned pre = (unsigned)b1_sh;
  size_t sbase = (size_t)s * NPS;
  const uint4* U4 = (const uint4*)(HT + sbase);
  float4* X4 = (float4*)(Xo + sbase);
  for (int i4 = chunk * 256 + tid; i4 < NPS / 4; i4 += 32 * 256) {
    uint4 v = U4[i4];
    unsigned uu[4] = {v.x, v.y, v.z, v.w};
    float oo[4];
#pragma unroll
    for (int t = 0; t < 4; ++t) {
      int il = i4 * 4 + t;
      unsigned u = uu[t] & 0x7fffffffu;
      unsigned bin = u >> 20;
      float val = __uint_as_float(uu[t]);
      if (bin > pre) {
        oo[t] = val;
        if (emit) {
          int pos = atomicAdd(&kcnt, 1);
          if (pos < 2048) { kidx[pos] = il; kval[pos] = val; }
        }
      } else if (bin < pre) {
        oo[t] = 0.0f;
      } else {
        oo[t] = val;
        atomicAdd(&h[(u >> 10) & 1023], 1u);
        int pos = atomicAdd(&lcnt, 1);
        if (pos < 4096) lidx[pos] = il;
      }
    }
    X4[i4] = make_float4(oo[0], oo[1], oo[2], oo[3]);
  }
  __syncthreads();
  if (tid == 0) {
    int n = lcnt < 4096 ? lcnt : 4096;
    lbase = atomicAdd(&candcnt[s], n);
    if (emit) {
      int kn = kcnt < 2048 ? kcnt : 2048;
      kbase = atomicAdd(&nzcnt[s], kn);
    }
  }
  __syncthreads();
  int n = lcnt < 4096 ? lcnt : 4096;
  for (int e = tid; e < n; e += 256) {
    int g = lbase + e;
    if (g < CANDCAP) cand[s * CANDCAP + g] = lidx[e];
  }
  if (emit) {
    int kn = kcnt < 2048 ? kcnt : 2048;
    for (int e = tid; e < kn; e += 256) {
      int g = kbase + e;
      if (g < KSEL) { nzidx[s * KSEL + g] = kidx[e]; nzval[s * KSEL + g] = kval[e]; }
    }
  }
  for (int e = tid; e < 1024; e += 256)
    if (h[e]) atomicAdd(&g2[s * 1024 + e], h[e]);
}

// ---------------------------------------------------------------------------
// pass3_k: find1 + find2 + level-3 + tie resolution + candidate fixup in
// Xout + nz-list completion + per-sample state reset. Verified r12, unchanged.
// ---------------------------------------------------------------------------
__global__ __launch_bounds__(256) void pass3_k(const float* __restrict__ HT,
    const int* __restrict__ cand, int* __restrict__ candcnt,
    unsigned* __restrict__ g1, unsigned* __restrict__ g2,
    float* __restrict__ Xo, int* __restrict__ nzidx, float* __restrict__ nzval,
    int* __restrict__ nzcnt, int emit) {
  int s = blockIdx.x;
  __shared__ unsigned h[1024];
  __shared__ unsigned part[256];
  __shared__ int eqidx[1024];
  __shared__ int kidx[2048];
  __shared__ float kval[2048];
  __shared__ int eqn, kcnt, kbase;
  __shared__ unsigned tau_sh;
  __shared__ int k3_sh, cutoff_sh;
  __shared__ int b1_sh, k1_sh, b2_sh, k2_sh;
  int t = threadIdx.x;
  unsigned* hg1 = g1 + (size_t)s * 2048;
  unsigned s1 = 0;
#pragma unroll
  for (int e = 0; e < 8; ++e) s1 += hg1[t * 8 + e];
  part[t] = s1;
  for (int e = t; e < 1024; e += 256) h[e] = 0;
  if (t == 0) { eqn = 0; kcnt = 0; }
  __syncthreads();
  if (t == 0) {
    int Kv = KSEL;
    unsigned cumBefore = 0;
    int bsel = 0;
    for (int q = 255; q >= 0; --q) {
      unsigned ps = part[q];
      if ((int)(cumBefore + ps) >= Kv) {
        for (int e = q * 8 + 7;; --e) {
          unsigned c2 = cumBefore + hg1[e];
          if ((int)c2 >= Kv) { bsel = e; break; }
          cumBefore = c2;
        }
        break;
      }
      cumBefore += ps;
    }
    b1_sh = bsel;
    k1_sh = Kv - (int)cumBefore;
  }
  __syncthreads();
  unsigned* hg = g2 + s * 1024;
  unsigned s2 = 0;
#pragma unroll
  for (int e = 0; e < 4; ++e) s2 += hg[t * 4 + e];
  part[t] = s2;
  __syncthreads();
  if (t == 0) {
    int Kv = k1_sh;
    unsigned cumBefore = 0;
    int bsel = 0;
    for (int q = 255; q >= 0; --q) {
      unsigned ps = part[q];
      if ((int)(cumBefore + ps) >= Kv) {
        for (int e = q * 4 + 3;; --e) {
          unsigned c2 = cumBefore + hg[e];
          if ((int)c2 >= Kv) { bsel = e; break; }
          cumBefore = c2;
        }
        break;
      }
      cumBefore += ps;
    }
    b2_sh = bsel;
    k2_sh = Kv - (int)cumBefore;
  }
  __syncthreads();
  int n = candcnt[s];
  if (n > CANDCAP) n = CANDCAP;
  unsigned pre21 = (((unsigned)b1_sh) << 10) | (unsigned)b2_sh;
  const unsigned* U = (const unsigned*)(HT + (size_t)s * NPS);
  for (int e = t; e < n; e += 256) {
    int i = cand[s * CANDCAP + e];
    unsigned u = U[i] & 0x7fffffffu;
    if ((u >> 10) == pre21) atomicAdd(&h[u & 1023], 1u);
  }
  __syncthreads();
  if (t == 0) {
    int Kv = k2_sh;
    unsigned cumBefore = 0;
    int b3 = 0;
    for (int e = 1023; e >= 0; --e) {
      unsigned c2 = cumBefore + h[e];
      if ((int)c2 >= Kv) { b3 = e; break; }
      cumBefore = c2;
    }
    tau_sh = (pre21 << 10) | (unsigned)b3;
    k3_sh = Kv - (int)cumBefore;
  }
  __syncthreads();
  unsigned tau = tau_sh;
  for (int e = t; e < n; e += 256) {
    int i = cand[s * CANDCAP + e];
    unsigned u = U[i] & 0x7fffffffu;
    if (u == tau) {
      int pos = atomicAdd(&eqn, 1);
      if (pos < 1024) eqidx[pos] = i;
    }
  }
  __syncthreads();
  if (t == 0) {
    int m = eqn < 1024 ? eqn : 1024;
    int k3 = k3_sh;
    int cutoff;
    if (k3 >= m) {
      cutoff = 0x7fffffff;
    } else {
      int last = -1;
      for (int r = 0; r < k3; ++r) {
        int mn = 0x7fffffff;
        for (int q = 0; q < m; ++q) {
          int v = eqidx[q];
          if (v > last && v < mn) mn = v;
        }
        last = mn;
      }
      cutoff = last;
    }
    cutoff_sh = cutoff;
  }
  __syncthreads();
  int co = cutoff_sh;
  float* Xs = Xo + (size_t)s * NPS;
  for (int e = t; e < n; e += 256) {
    int i = cand[s * CANDCAP + e];
    unsigned uval = U[i];
    unsigned u = uval & 0x7fffffffu;
    bool keep = (u > tau) || (u == tau && i <= co);
    float val = __uint_as_float(uval);
    Xs[i] = keep ? val : 0.0f;
    if (keep && emit) {
      int pos = atomicAdd(&kcnt, 1);
      if (pos < 2048) { kidx[pos] = i; kval[pos] = val; }
    }
  }
  __syncthreads();
  if (emit) {
    if (t == 0) {
      int kn = kcnt < 2048 ? kcnt : 2048;
      kbase = atomicAdd(&nzcnt[s], kn);
    }
    __syncthreads();
    int kn = kcnt < 2048 ? kcnt : 2048;
    for (int e = t; e < kn; e += 256) {
      int g = kbase + e;
      if (g < KSEL) { nzidx[s * KSEL + g] = kidx[e]; nzval[s * KSEL + g] = kval[e]; }
    }
  }
  __syncthreads();
  for (int e = t; e < 2048; e += 256) hg1[e] = 0;
  for (int e = t; e < 1024; e += 256) hg[e] = 0;
  if (t == 0) { candcnt[s] = 0; nzcnt[s] = 0; }
}

extern "C" void kernel_launch(void* const* d_in, const int* in_sizes, int n_in,
                              void* d_out, int out_size, void* d_ws, size_t ws_size,
                              hipStream_t stream) {
  const float* Y  = (const float*)d_in[0];
  const float* X0 = (const float*)d_in[1];
  const float* Wg = (const float*)d_in[2];
  float* Xout = (float*)d_out;

  double* WDd  = (double*)d_ws;                        // NW f64
  double* Wt2d = WDd + NW;                             // NW f64
  float* HT   = (float*)(Wt2d + NW);                   // NTOT f32
  float* Rbuf = HT + NTOT;                             // RTOT f32
  double* Rd  = (double*)(Rbuf + RTOT);                // RTOT f64
  unsigned* g1 = (unsigned*)(Rd + RTOT);               // 32*2048
  unsigned* g2 = g1 + 32 * 2048;                       // 32*1024
  int* candcnt = (int*)(g2 + 32 * 1024);               // 32
  int* nzcnt = candcnt + 32;                           // 32
  int* cand = nzcnt + 32;                              // 32*CANDCAP
  int* nzidx = cand + 32 * CANDCAP;                    // 32*KSEL
  float* nzval = (float*)(nzidx + 32 * KSEL);          // 32*KSEL
  double* prg = (double*)(nzval + 32 * KSEL);          // 64*64*4 f64 probe buf
  int* tabs = (int*)(prg + 64 * 64 * 4);               // 769 ints

  prep_k<<<dim3((RTOT + 255) / 256), dim3(256), 0, stream>>>(Wg, WDd, Wt2d, Y, Rd, g1);
  mfprobe_k<<<dim3(1), dim3(64), 0, stream>>>(prg, tabs);

  for (int it = 0; it < 3; ++it) {
    const float* Xsrc = (it == 0) ? X0 : (const float*)Xout;
    if (it == 0) {
      convD_k<<<dim3(2048), dim3(256), 0, stream>>>(Xsrc, WDd, Rd);
      convDtMM_k<double><<<dim3(1824), dim3(256), 0, stream>>>(
          Rd, Wt2d, Xsrc, HT, g1, tabs);
    } else {
      convD_sparse_k<<<dim3(BATCH * CCH * 8), dim3(256), 0, stream>>>(
          Wg, nzidx, nzval, Y, Rbuf);
      convDtMM_k<float><<<dim3(1824), dim3(256), 0, stream>>>(
          Rbuf, Wt2d, Xsrc, HT, g1, tabs);
    }
    int emit = (it < 2) ? 1 : 0;
    histwrite_k<<<dim3(BATCH * 32), dim3(256), 0, stream>>>(
        HT, g1, g2, cand, candcnt, Xout, nzidx, nzval, nzcnt, emit);
    pass3_k<<<dim3(BATCH), dim3(256), 0, stream>>>(
        HT, cand, candcnt, g1, g2, Xout, nzidx, nzval, nzcnt, emit);
  }
}

// Round 14
// 1107.932 us; speedup vs baseline: 1.2058x; 1.2058x over previous
//
#include <hip/hip_runtime.h>

#define BATCH 32
#define ATOMS 128
#define CCH 3
#define XH 57
#define XW 57
#define OHH 64
#define OWW 64
#define KSEL 2000
#define PIX (XH*XW)            // 3249
#define NPS (ATOMS*PIX)        // 415872 per-sample X elements
#define NTOT (BATCH*NPS)       // 13307904
#define RPS (CCH*OHH*OWW)      // 12288 per-sample R elements
#define RTOT (BATCH*RPS)       // 393216
#define CANDCAP 32768
#define NW 24576               // weight elements 128*3*8*8
#define ZWORDS (32*2048*2 + 32)  // g1 + g1x + candcnt

// ---------------------------------------------------------------------------
// Prep (once): WDd f64 (convD), Wt2f f32 (convDt/recompute), Rd = -Y,
// zero g1/g1x/candcnt.
// ---------------------------------------------------------------------------
__global__ __launch_bounds__(256) void prep_k(const float* __restrict__ Wg,
    double* __restrict__ WDd, float* __restrict__ Wt2f,
    const float* __restrict__ Y, double* __restrict__ Rd,
    unsigned* __restrict__ zbuf) {
  int e = blockIdx.x * 256 + threadIdx.x;
  if (e < NW) {
    {
      int kw = e & 7; int t = e >> 3; int c = t % 3; t /= 3; int kh = t & 7; int a = t >> 3;
      WDd[e] = (double)Wg[(a*3 + c)*64 + kh*8 + kw];
    }
    {
      int a = e & 127; int t = e >> 7; int j = t & 7; int i = (t >> 3) & 7; int c = t >> 6;
      Wt2f[e] = Wg[(a*3 + c)*64 + j*8 + i];   // [c][i][j][a], exact f32
    }
  }
  if (e < RTOT) Rd[e] = -(double)Y[e];
  if (e < ZWORDS) zbuf[e] = 0;
}

// ---------------------------------------------------------------------------
// DENSE R += D(X) (iteration 0 only). Verified r11/r12 version, unchanged.
// ---------------------------------------------------------------------------
__global__ __launch_bounds__(256) void convD_k(const float* __restrict__ X,
    const double* __restrict__ WDd, double* __restrict__ Rd) {
  __shared__ double Xs[4][11][72];            // 25344 B
  int p = blockIdx.x;
  int lg = (p & 7) * 256 + (p >> 3);          // bijective: 2048 = 8*256
  int b = lg >> 6; int rem = lg & 63;
  int band = rem >> 2, quarter = rem & 3;
  int row0 = band * 4;
  int a_base = quarter * 32;
  int tid = threadIdx.x;
  int ox = tid & 63;
  int wv = __builtin_amdgcn_readfirstlane(tid >> 6);
  const float* Xb = X + (size_t)b * NPS;

  double acc[4][3];
#pragma unroll
  for (int ty = 0; ty < 4; ++ty)
#pragma unroll
    for (int c = 0; c < 3; ++c) acc[ty][c] = 0.0;

  for (int ch = 0; ch < 8; ++ch) {
    __syncthreads();
    for (int e = tid; e < 4 * 11 * 72; e += 256) {
      int ai = e / 792; int rem2 = e - ai * 792;
      int r = rem2 / 72; int ss = rem2 - r * 72;
      int gy = row0 - 7 + r;
      int xcol = ss - 7;
      int a = a_base + ch * 4 + ai;
      float v = 0.0f;
      if ((unsigned)xcol < (unsigned)XW && (unsigned)gy < (unsigned)XH)
        v = Xb[a * PIX + gy * XW + xcol];
      Xs[ai][r][ss] = (double)v;
    }
    __syncthreads();
    {
      int a = a_base + ch * 4 + wv;
      const double* Wa = WDd + a * 192;       // [kh][c][kw]
#pragma unroll
      for (int r = 0; r < 11; ++r) {
        int gy = row0 - 7 + r;
        if ((unsigned)gy >= (unsigned)XH) continue;   // uniform
        double xd[8];
#pragma unroll
        for (int t = 0; t < 8; ++t) xd[t] = Xs[wv][r][ox + t];
#pragma unroll
        for (int ty = 0; ty < 4; ++ty) {
          int kh = ty + 7 - r;
          if ((unsigned)kh < 8u) {
            const double* Wk = Wa + kh * 24;
#pragma unroll
            for (int kw = 0; kw < 8; ++kw) {
              acc[ty][0] = fma(xd[7 - kw], Wk[kw],      acc[ty][0]);
              acc[ty][1] = fma(xd[7 - kw], Wk[8 + kw],  acc[ty][1]);
              acc[ty][2] = fma(xd[7 - kw], Wk[16 + kw], acc[ty][2]);
            }
          }
        }
      }
    }
  }
#pragma unroll
  for (int ty = 0; ty < 4; ++ty) {
    int oy = row0 + ty;
#pragma unroll
    for (int c = 0; c < 3; ++c)
      atomicAdd(&Rd[((size_t)(b * CCH + c) << 12) + (oy << 6) + ox], acc[ty][c]);
  }
}

// ---------------------------------------------------------------------------
// SPARSE R = D(X) - Y (iterations 1,2). Verified, unchanged.
// ---------------------------------------------------------------------------
__global__ __launch_bounds__(256) void convD_sparse_k(const float* __restrict__ Wg,
    const int* __restrict__ nzidx, const float* __restrict__ nzval,
    const float* __restrict__ Y, float* __restrict__ R) {
  __shared__ double accd[512];       // [rr][ox]
  __shared__ float Wf[8192];         // [a][kh][kw] for this c
  __shared__ int   li[KSEL];
  __shared__ float lv[KSEL];
  int p = blockIdx.x;
  int lg = (p & 7) * 96 + (p >> 3);  // bijective: 768 = 8*96
  int s = lg / 24; int r = lg % 24; int c = r >> 3; int band = r & 7;
  int row0 = band * 8;
  int tid = threadIdx.x;
  for (int e = tid; e < 512; e += 256) accd[e] = 0.0;
  for (int e = tid; e < 8192; e += 256) {
    int a = e >> 6, k2 = e & 63;
    Wf[e] = Wg[(a * 3 + c) * 64 + k2];
  }
  for (int e = tid; e < KSEL; e += 256) {
    li[e] = nzidx[s * KSEL + e];
    lv[e] = nzval[s * KSEL + e];
  }
  __syncthreads();
  int slot = tid >> 3, kw = tid & 7;
  for (int e = slot; e < KSEL; e += 32) {
    int idx = li[e];
    int a = (int)((unsigned)idx / 3249u);
    int pp = idx - a * 3249;
    int y = (int)((unsigned)pp / 57u);
    int x = pp - y * 57;
    int dy = y - row0;
    if (dy < -7 || dy > 7) continue;
    double val = (double)lv[e];
    const float* wp = Wf + (a << 6) + kw;
#pragma unroll
    for (int kh = 0; kh < 8; ++kh) {
      int rr = dy + kh;
      if ((unsigned)rr < 8u)
        __hip_atomic_fetch_add(&accd[(rr << 6) + x + kw],
                               val * (double)wp[kh << 3],
                               __ATOMIC_RELAXED, __HIP_MEMORY_SCOPE_WORKGROUP);
    }
  }
  __syncthreads();
  const float* Yb = Y + (((size_t)(s * CCH + c)) << 12) + (row0 << 6);
  float* Rb = R + (((size_t)(s * CCH + c)) << 12) + (row0 << 6);
  for (int e = tid; e < 512; e += 256)
    Rb[e] = (float)(accd[e] - (double)Yb[e]);
}

// ---------------------------------------------------------------------------
// HT~ = Xprev - Dt(R) in f32 (approx; classification only), fused L1 hist.
// Same structure as the verified r12 f64 kernel, dtype changed. Uniform
// s_load f32 weights (no per-use cvt since FMA is f32 now).
// ---------------------------------------------------------------------------
template <typename TR>
__global__ __launch_bounds__(256) void convDt_k(const TR* __restrict__ R,
    const float* __restrict__ Wt2f, const float* __restrict__ Xprev,
    float* __restrict__ HT, unsigned* __restrict__ g1) {
  __shared__ float Rl[3][15][72];
  __shared__ unsigned hh[1024];      // packed: 2 u16 bins per word
  int p = blockIdx.x;
  int lg = (p & 7) * 512 + (p >> 3);  // bijective: 4096 = 8*512
  int b = lg >> 7; int rem = lg & 127; int ag = rem >> 3; int by = rem & 7;
  int row0 = by * 8;
  int a0 = ag * 8;
  int tid = threadIdx.x;
  for (int e = tid; e < 1024; e += 256) hh[e] = 0;
  for (int e = tid; e < 3 * 15 * 72; e += 256) {
    int c = e / (15 * 72); int r2 = e - c * (15 * 72);
    int rr = r2 / 72; int cc = r2 - rr * 72;
    int gr = row0 + rr;
    float v = 0.0f;
    if (cc < OWW && gr < OHH)
      v = (float)R[((size_t)(b * CCH + c) << 12) + (gr << 6) + cc];
    Rl[c][rr][cc] = v;
  }
  __syncthreads();
  int x = tid & 63, yg = tid >> 6;
  int yb = yg * 2;
  float acc[8][2];
#pragma unroll
  for (int aa = 0; aa < 8; ++aa) { acc[aa][0] = 0.0f; acc[aa][1] = 0.0f; }

#pragma unroll 1
  for (int c = 0; c < 3; ++c) {
#pragma unroll 1
    for (int j = 0; j < 8; ++j) {
      float rw[9];
#pragma unroll
      for (int r = 0; r < 9; ++r) rw[r] = Rl[c][yb + r][x + j];
#pragma unroll
      for (int i = 0; i < 8; ++i) {
        const float* wp = Wt2f + ((c * 8 + i) * 8 + j) * 128 + a0;  // uniform
#pragma unroll
        for (int aa = 0; aa < 8; ++aa) {
          float w = wp[aa];
          acc[aa][0] = fmaf(rw[i + 0], w, acc[aa][0]);
          acc[aa][1] = fmaf(rw[i + 1], w, acc[aa][1]);
        }
      }
    }
  }
  if (x < XW) {
#pragma unroll
    for (int ty = 0; ty < 2; ++ty) {
      int yy = row0 + yb + ty;
      if (yy < XH) {
#pragma unroll
        for (int aa = 0; aa < 8; ++aa) {
          size_t xo = (size_t)(b * ATOMS + a0 + aa) * PIX + yy * XW + x;
          float fv = Xprev[xo] - acc[aa][ty];
          HT[xo] = fv;
          unsigned u = __float_as_uint(fv) & 0x7fffffffu;
          unsigned bin = u >> 20;
          atomicAdd(&hh[bin >> 1], 1u << ((bin & 1) << 4));
        }
      }
    }
  }
  __syncthreads();
  unsigned* gp = g1 + (size_t)b * 2048;
  for (int e = tid; e < 1024; e += 256) {
    unsigned v = hh[e];
    unsigned lo = v & 0xffffu, hi = v >> 16;
    if (lo) atomicAdd(&gp[2 * e], lo);
    if (hi) atomicAdd(&gp[2 * e + 1], hi);
  }
}

// ---------------------------------------------------------------------------
// histwrite_k: classify every element by APPROX bin vs the safety band:
//   bin <  b1-1 -> certainly out: Xout = 0
//   bin >= b1-1 -> candidate (includes all potential keeps): Xout placeholder,
//                  appended to cand list (pass3 resolves with exact values).
// Band margin (1 full bin ~ tau/4) >> f32 error (~1e-3) -> classification
// agrees with exact for all non-candidates.
// ---------------------------------------------------------------------------
__global__ __launch_bounds__(256) void histwrite_k(const float* __restrict__ HT,
    const unsigned* __restrict__ g1, int* __restrict__ cand,
    int* __restrict__ candcnt, float* __restrict__ Xo) {
  __shared__ unsigned part[256];
  __shared__ int lidx[4096];
  __shared__ int lcnt, lbase, b1_sh;
  int tid = threadIdx.x;
  int s = blockIdx.x >> 5;
  int chunk = blockIdx.x & 31;
  const unsigned* hg1 = g1 + (size_t)s * 2048;
  unsigned psum = 0;
#pragma unroll
  for (int e = 0; e < 8; ++e) psum += hg1[tid * 8 + e];
  part[tid] = psum;
  if (tid == 0) lcnt = 0;
  __syncthreads();
  if (tid == 0) {
    int Kv = KSEL;
    unsigned cumBefore = 0;
    int bsel = 0;
    for (int q = 255; q >= 0; --q) {
      unsigned ps = part[q];
      if ((int)(cumBefore + ps) >= Kv) {
        for (int e = q * 8 + 7;; --e) {
          unsigned c2 = cumBefore + hg1[e];
          if ((int)c2 >= Kv) { bsel = e; break; }
          cumBefore = c2;
        }
        break;
      }
      cumBefore += ps;
    }
    b1_sh = bsel;
  }
  __syncthreads();
  unsigned blo = (unsigned)(b1_sh > 0 ? b1_sh - 1 : 0);
  size_t sbase = (size_t)s * NPS;
  const uint4* U4 = (const uint4*)(HT + sbase);
  float4* X4 = (float4*)(Xo + sbase);
  for (int i4 = chunk * 256 + tid; i4 < NPS / 4; i4 += 32 * 256) {
    uint4 v = U4[i4];
    unsigned uu[4] = {v.x, v.y, v.z, v.w};
    float oo[4];
#pragma unroll
    for (int t = 0; t < 4; ++t) {
      int il = i4 * 4 + t;
      unsigned u = uu[t] & 0x7fffffffu;
      unsigned bin = u >> 20;
      if (bin >= blo) {
        oo[t] = __uint_as_float(uu[t]);       // placeholder, pass3 overwrites
        int pos = atomicAdd(&lcnt, 1);
        if (pos < 4096) lidx[pos] = il;
      } else {
        oo[t] = 0.0f;
      }
    }
    X4[i4] = make_float4(oo[0], oo[1], oo[2], oo[3]);
  }
  __syncthreads();
  if (tid == 0) {
    int n = lcnt < 4096 ? lcnt : 4096;
    lbase = atomicAdd(&candcnt[s], n);
  }
  __syncthreads();
  int n = lcnt < 4096 ? lcnt : 4096;
  for (int e = tid; e < n; e += 256) {
    int g = lbase + e;
    if (g < CANDCAP) cand[s * CANDCAP + g] = lidx[e];
  }
}

// ---------------------------------------------------------------------------
// recompute_k: EXACT f64 re-evaluation of every candidate (same math as the
// verified r12 f64 convDt: same R buffers, f64 weights=(double)Wt2f exact,
// Xprev from prev nz list via LDS hash (it>=1) or X0 (it==0)). Writes
// f32-rounded exact value to candval + hist of its top-11 bits to g1x.
// grid = 32 samples x 8 chunks.
// ---------------------------------------------------------------------------
template <typename TR, bool SPX>
__global__ __launch_bounds__(256) void recompute_k(const TR* __restrict__ R,
    const float* __restrict__ Wt2f, const float* __restrict__ X0,
    const int* __restrict__ pnzidx, const float* __restrict__ pnzval,
    const int* __restrict__ cand, const int* __restrict__ candcnt,
    float* __restrict__ candval, unsigned* __restrict__ g1x) {
  __shared__ int hidx[4096];
  __shared__ float hval[4096];
  __shared__ unsigned hx[2048];
  int s = blockIdx.x >> 3;
  int chunk = blockIdx.x & 7;
  int tid = threadIdx.x;
  for (int e = tid; e < 2048; e += 256) hx[e] = 0;
  if constexpr (SPX) {
    for (int e = tid; e < 4096; e += 256) hidx[e] = -1;
    __syncthreads();
    for (int e = tid; e < KSEL; e += 256) {
      int idx = pnzidx[s * KSEL + e];
      float v = pnzval[s * KSEL + e];
      int slot = idx & 4095;
      while (true) {
        int old = atomicCAS(&hidx[slot], -1, idx);
        if (old == -1) { hval[slot] = v; break; }
        slot = (slot + 1) & 4095;
      }
    }
  }
  __syncthreads();
  int n = candcnt[s];
  if (n > CANDCAP) n = CANDCAP;
  const TR* Rb = R + ((size_t)(s * 3) << 12);
  for (int e = chunk * 256 + tid; e < n; e += 2048) {
    int i = cand[s * CANDCAP + e];
    int a = (int)((unsigned)i / 3249u);
    int p = i - a * 3249;
    int y = (int)((unsigned)p / 57u);
    int x = p - y * 57;
    double xprev;
    if constexpr (SPX) {
      xprev = 0.0;
      int slot = i & 4095;
      while (true) {
        int h = hidx[slot];
        if (h == i) { xprev = (double)hval[slot]; break; }
        if (h == -1) break;
        slot = (slot + 1) & 4095;
      }
    } else {
      xprev = (double)X0[(size_t)s * NPS + i];
    }
    double acc = 0.0;
    for (int c = 0; c < 3; ++c) {
#pragma unroll
      for (int ii = 0; ii < 8; ++ii) {
        const TR* rrow = Rb + (c << 12) + ((y + ii) << 6) + x;
        const float* wrow = Wt2f + ((c * 8 + ii) * 8) * 128 + a;
#pragma unroll
        for (int jj = 0; jj < 8; ++jj)
          acc = fma((double)rrow[jj], (double)wrow[jj * 128], acc);
      }
    }
    float cf = (float)(xprev - acc);
    candval[s * CANDCAP + e] = cf;
    unsigned u = __float_as_uint(cf) & 0x7fffffffu;
    atomicAdd(&hx[u >> 20], 1u);
  }
  __syncthreads();
  unsigned* gp = g1x + (size_t)s * 2048;
  for (int e = tid; e < 2048; e += 256)
    if (hx[e]) atomicAdd(&gp[e], hx[e]);
}

// ---------------------------------------------------------------------------
// pass3_k: exact 3-level radix select over the candidate set (using the
// recomputed exact values), tie resolution by lowest index, fixup of Xout,
// nz-list emission (exactly KSEL entries), per-sample state reset.
// ---------------------------------------------------------------------------
__global__ __launch_bounds__(256) void pass3_k(const int* __restrict__ cand,
    int* __restrict__ candcnt, const float* __restrict__ candval,
    unsigned* __restrict__ g1, unsigned* __restrict__ g1x,
    float* __restrict__ Xo, int* __restrict__ nzidx, float* __restrict__ nzval,
    int emit) {
  int s = blockIdx.x;
  __shared__ unsigned h[1024];
  __shared__ unsigned part[256];
  __shared__ int eqidx[1024];
  __shared__ int kidx[2048];
  __shared__ float kval[2048];
  __shared__ int eqn, kcnt;
  __shared__ unsigned tau_sh;
  __shared__ int k3_sh, cutoff_sh, b1_sh, k1_sh, b2_sh, k2_sh;
  int t = threadIdx.x;
  unsigned* hx = g1x + (size_t)s * 2048;
  unsigned s1 = 0;
#pragma unroll
  for (int e = 0; e < 8; ++e) s1 += hx[t * 8 + e];
  part[t] = s1;
  for (int e = t; e < 1024; e += 256) h[e] = 0;
  if (t == 0) { eqn = 0; kcnt = 0; }
  __syncthreads();
  if (t == 0) {
    int Kv = KSEL;
    unsigned cumBefore = 0;
    int bsel = 0;
    for (int q = 255; q >= 0; --q) {
      unsigned ps = part[q];
      if ((int)(cumBefore + ps) >= Kv) {
        for (int e = q * 8 + 7;; --e) {
          unsigned c2 = cumBefore + hx[e];
          if ((int)c2 >= Kv) { bsel = e; break; }
          cumBefore = c2;
        }
        break;
      }
      cumBefore += ps;
    }
    b1_sh = bsel;
    k1_sh = KSEL - (int)cumBefore;
  }
  __syncthreads();
  int n = candcnt[s];
  if (n > CANDCAP) n = CANDCAP;
  const int* cs = cand + s * CANDCAP;
  const float* cv = candval + s * CANDCAP;
  unsigned b1x = (unsigned)b1_sh;
  // level 2 among candidates with exact top-11 == b1x
  for (int e = t; e < n; e += 256) {
    unsigned u = __float_as_uint(cv[e]) & 0x7fffffffu;
    if ((u >> 20) == b1x) atomicAdd(&h[(u >> 10) & 1023], 1u);
  }
  __syncthreads();
  part[t] = h[t * 4] + h[t * 4 + 1] + h[t * 4 + 2] + h[t * 4 + 3];
  __syncthreads();
  if (t == 0) {
    int Kv = k1_sh;
    unsigned cumBefore = 0;
    int bsel = 0;
    for (int q = 255; q >= 0; --q) {
      unsigned ps = part[q];
      if ((int)(cumBefore + ps) >= Kv) {
        for (int e = q * 4 + 3;; --e) {
          unsigned c2 = cumBefore + h[e];
          if ((int)c2 >= Kv) { bsel = e; break; }
          cumBefore = c2;
        }
        break;
      }
      cumBefore += ps;
    }
    b2_sh = bsel;
    k2_sh = Kv - (int)cumBefore;
  }
  __syncthreads();
  for (int e = t; e < 1024; e += 256) h[e] = 0;
  __syncthreads();
  unsigned pre21 = (b1x << 10) | (unsigned)b2_sh;
  for (int e = t; e < n; e += 256) {
    unsigned u = __float_as_uint(cv[e]) & 0x7fffffffu;
    if ((u >> 10) == pre21) atomicAdd(&h[u & 1023], 1u);
  }
  __syncthreads();
  if (t == 0) {
    int Kv = k2_sh;
    unsigned cumBefore = 0;
    int b3 = 0;
    for (int e = 1023; e >= 0; --e) {
      unsigned c2 = cumBefore + h[e];
      if ((int)c2 >= Kv) { b3 = e; break; }
      cumBefore = c2;
    }
    tau_sh = (pre21 << 10) | (unsigned)b3;
    k3_sh = Kv - (int)cumBefore;
  }
  __syncthreads();
  unsigned tau = tau_sh;
  for (int e = t; e < n; e += 256) {
    unsigned u = __float_as_uint(cv[e]) & 0x7fffffffu;
    if (u == tau) {
      int pos = atomicAdd(&eqn, 1);
      if (pos < 1024) eqidx[pos] = cs[e];
    }
  }
  __syncthreads();
  if (t == 0) {
    int m = eqn < 1024 ? eqn : 1024;
    int k3 = k3_sh;
    int cutoff;
    if (k3 >= m) {
      cutoff = 0x7fffffff;
    } else {
      int last = -1;
      for (int r = 0; r < k3; ++r) {
        int mn = 0x7fffffff;
        for (int q = 0; q < m; ++q) {
          int v = eqidx[q];
          if (v > last && v < mn) mn = v;
        }
        last = mn;
      }
      cutoff = last;
    }
    cutoff_sh = cutoff;
  }
  __syncthreads();
  int co = cutoff_sh;
  float* Xs = Xo + (size_t)s * NPS;
  for (int e = t; e < n; e += 256) {
    int i = cs[e];
    float cf = cv[e];
    unsigned u = __float_as_uint(cf) & 0x7fffffffu;
    bool keep = (u > tau) || (u == tau && i <= co);
    Xs[i] = keep ? cf : 0.0f;
    if (keep && emit) {
      int pos = atomicAdd(&kcnt, 1);
      if (pos < 2048) { kidx[pos] = i; kval[pos] = cf; }
    }
  }
  __syncthreads();
  if (emit) {
    int kn = kcnt < KSEL ? kcnt : KSEL;
    for (int e = t; e < kn; e += 256) {
      nzidx[s * KSEL + e] = kidx[e];
      nzval[s * KSEL + e] = kval[e];
    }
  }
  // reset per-sample state for the next iteration
  unsigned* hg1 = g1 + (size_t)s * 2048;
  for (int e = t; e < 2048; e += 256) { hg1[e] = 0; hx[e] = 0; }
  if (t == 0) candcnt[s] = 0;
}

extern "C" void kernel_launch(void* const* d_in, const int* in_sizes, int n_in,
                              void* d_out, int out_size, void* d_ws, size_t ws_size,
                              hipStream_t stream) {
  const float* Y  = (const float*)d_in[0];
  const float* X0 = (const float*)d_in[1];
  const float* Wg = (const float*)d_in[2];
  float* Xout = (float*)d_out;

  double* WDd  = (double*)d_ws;                        // NW f64
  float* Wt2f  = (float*)(WDd + NW);                   // NW f32
  float* HT   = Wt2f + NW;                             // NTOT f32
  float* Rbuf = HT + NTOT;                             // RTOT f32
  double* Rd  = (double*)(Rbuf + RTOT);                // RTOT f64
  unsigned* g1 = (unsigned*)(Rd + RTOT);               // 32*2048
  unsigned* g1x = g1 + 32 * 2048;                      // 32*2048
  int* candcnt = (int*)(g1x + 32 * 2048);              // 32
  int* cand = candcnt + 32;                            // 32*CANDCAP
  float* candval = (float*)(cand + 32 * CANDCAP);      // 32*CANDCAP
  int* nzidx = (int*)(candval + 32 * CANDCAP);         // 32*KSEL
  float* nzval = (float*)(nzidx + 32 * KSEL);          // 32*KSEL

  prep_k<<<dim3((RTOT + 255) / 256), dim3(256), 0, stream>>>(Wg, WDd, Wt2f, Y, Rd, g1);

  for (int it = 0; it < 3; ++it) {
    if (it == 0) {
      convD_k<<<dim3(2048), dim3(256), 0, stream>>>(X0, WDd, Rd);
      convDt_k<double><<<dim3(4096), dim3(256), 0, stream>>>(Rd, Wt2f, X0, HT, g1);
    } else {
      convD_sparse_k<<<dim3(BATCH * CCH * 8), dim3(256), 0, stream>>>(
          Wg, nzidx, nzval, Y, Rbuf);
      convDt_k<float><<<dim3(4096), dim3(256), 0, stream>>>(Rbuf, Wt2f,
          (const float*)Xout, HT, g1);
    }
    histwrite_k<<<dim3(BATCH * 32), dim3(256), 0, stream>>>(
        HT, g1, cand, candcnt, Xout);
    if (it == 0) {
      recompute_k<double, false><<<dim3(BATCH * 8), dim3(256), 0, stream>>>(
          Rd, Wt2f, X0, nullptr, nullptr, cand, candcnt, candval, g1x);
    } else {
      recompute_k<float, true><<<dim3(BATCH * 8), dim3(256), 0, stream>>>(
          Rbuf, Wt2f, X0, nzidx, nzval, cand, candcnt, candval, g1x);
    }
    int emit = (it < 2) ? 1 : 0;
    pass3_k<<<dim3(BATCH), dim3(256), 0, stream>>>(
        cand, candcnt, candval, g1, g1x, Xout, nzidx, nzval, emit);
  }
}

// Round 15
// 955.249 us; speedup vs baseline: 1.3986x; 1.1598x over previous
//
#include <hip/hip_runtime.h>

#define BATCH 32
#define ATOMS 128
#define CCH 3
#define XH 57
#define XW 57
#define OHH 64
#define OWW 64
#define KSEL 2000
#define PIX (XH*XW)            // 3249
#define NPS (ATOMS*PIX)        // 415872 per-sample X elements
#define NTOT (BATCH*NPS)       // 13307904
#define RPS (CCH*OHH*OWW)      // 12288 per-sample R elements
#define RTOT (BATCH*RPS)       // 393216
#define CANDCAP 32768
#define NW 24576               // weight elements 128*3*8*8
#define NWC 32768              // Wcand padded: 128 atoms x 256
#define ZWORDS (32*2048*2 + 32)  // g1 + g1x + candcnt

// ---------------------------------------------------------------------------
// Prep (once): WDd f64 (convD), Wt2f f32 (convDt), Wcand f32 (recompute,
// contiguous 192 per atom), Rd = -Y, zero g1/g1x/candcnt.
// ---------------------------------------------------------------------------
__global__ __launch_bounds__(256) void prep_k(const float* __restrict__ Wg,
    double* __restrict__ WDd, float* __restrict__ Wt2f,
    float* __restrict__ Wcand, const float* __restrict__ Y,
    double* __restrict__ Rd, unsigned* __restrict__ zbuf) {
  int e = blockIdx.x * 256 + threadIdx.x;
  if (e < NW) {
    {
      int kw = e & 7; int t = e >> 3; int c = t % 3; t /= 3; int kh = t & 7; int a = t >> 3;
      WDd[e] = (double)Wg[(a*3 + c)*64 + kh*8 + kw];
    }
    {
      int a = e & 127; int t = e >> 7; int j = t & 7; int i = (t >> 3) & 7; int c = t >> 6;
      Wt2f[e] = Wg[(a*3 + c)*64 + j*8 + i];   // [c][i][j][a], exact f32
    }
  }
  if (e < NWC) {
    int a = e >> 8, r = e & 255;
    float v = 0.0f;
    if (r < 192) {
      int c = r >> 6, ii = (r >> 3) & 7, jj = r & 7;
      v = Wg[(a*3 + c)*64 + jj*8 + ii];       // Wcand[a][(c*8+ii)*8+jj]=W[a,c,jj,ii]
    }
    Wcand[e] = v;
  }
  if (e < RTOT) Rd[e] = -(double)Y[e];
  if (e < ZWORDS) zbuf[e] = 0;
}

// ---------------------------------------------------------------------------
// DENSE R += D(X) (iteration 0 only). Verified r11/r12 version, unchanged.
// ---------------------------------------------------------------------------
__global__ __launch_bounds__(256) void convD_k(const float* __restrict__ X,
    const double* __restrict__ WDd, double* __restrict__ Rd) {
  __shared__ double Xs[4][11][72];            // 25344 B
  int p = blockIdx.x;
  int lg = (p & 7) * 256 + (p >> 3);          // bijective: 2048 = 8*256
  int b = lg >> 6; int rem = lg & 63;
  int band = rem >> 2, quarter = rem & 3;
  int row0 = band * 4;
  int a_base = quarter * 32;
  int tid = threadIdx.x;
  int ox = tid & 63;
  int wv = __builtin_amdgcn_readfirstlane(tid >> 6);
  const float* Xb = X + (size_t)b * NPS;

  double acc[4][3];
#pragma unroll
  for (int ty = 0; ty < 4; ++ty)
#pragma unroll
    for (int c = 0; c < 3; ++c) acc[ty][c] = 0.0;

  for (int ch = 0; ch < 8; ++ch) {
    __syncthreads();
    for (int e = tid; e < 4 * 11 * 72; e += 256) {
      int ai = e / 792; int rem2 = e - ai * 792;
      int r = rem2 / 72; int ss = rem2 - r * 72;
      int gy = row0 - 7 + r;
      int xcol = ss - 7;
      int a = a_base + ch * 4 + ai;
      float v = 0.0f;
      if ((unsigned)xcol < (unsigned)XW && (unsigned)gy < (unsigned)XH)
        v = Xb[a * PIX + gy * XW + xcol];
      Xs[ai][r][ss] = (double)v;
    }
    __syncthreads();
    {
      int a = a_base + ch * 4 + wv;
      const double* Wa = WDd + a * 192;       // [kh][c][kw]
#pragma unroll
      for (int r = 0; r < 11; ++r) {
        int gy = row0 - 7 + r;
        if ((unsigned)gy >= (unsigned)XH) continue;   // uniform
        double xd[8];
#pragma unroll
        for (int t = 0; t < 8; ++t) xd[t] = Xs[wv][r][ox + t];
#pragma unroll
        for (int ty = 0; ty < 4; ++ty) {
          int kh = ty + 7 - r;
          if ((unsigned)kh < 8u) {
            const double* Wk = Wa + kh * 24;
#pragma unroll
            for (int kw = 0; kw < 8; ++kw) {
              acc[ty][0] = fma(xd[7 - kw], Wk[kw],      acc[ty][0]);
              acc[ty][1] = fma(xd[7 - kw], Wk[8 + kw],  acc[ty][1]);
              acc[ty][2] = fma(xd[7 - kw], Wk[16 + kw], acc[ty][2]);
            }
          }
        }
      }
    }
  }
#pragma unroll
  for (int ty = 0; ty < 4; ++ty) {
    int oy = row0 + ty;
#pragma unroll
    for (int c = 0; c < 3; ++c)
      atomicAdd(&Rd[((size_t)(b * CCH + c) << 12) + (oy << 6) + ox], acc[ty][c]);
  }
}

// ---------------------------------------------------------------------------
// SPARSE R = D(X) - Y (iterations 1,2). Verified, unchanged.
// ---------------------------------------------------------------------------
__global__ __launch_bounds__(256) void convD_sparse_k(const float* __restrict__ Wg,
    const int* __restrict__ nzidx, const float* __restrict__ nzval,
    const float* __restrict__ Y, float* __restrict__ R) {
  __shared__ double accd[512];       // [rr][ox]
  __shared__ float Wf[8192];         // [a][kh][kw] for this c
  __shared__ int   li[KSEL];
  __shared__ float lv[KSEL];
  int p = blockIdx.x;
  int lg = (p & 7) * 96 + (p >> 3);  // bijective: 768 = 8*96
  int s = lg / 24; int r = lg % 24; int c = r >> 3; int band = r & 7;
  int row0 = band * 8;
  int tid = threadIdx.x;
  for (int e = tid; e < 512; e += 256) accd[e] = 0.0;
  for (int e = tid; e < 8192; e += 256) {
    int a = e >> 6, k2 = e & 63;
    Wf[e] = Wg[(a * 3 + c) * 64 + k2];
  }
  for (int e = tid; e < KSEL; e += 256) {
    li[e] = nzidx[s * KSEL + e];
    lv[e] = nzval[s * KSEL + e];
  }
  __syncthreads();
  int slot = tid >> 3, kw = tid & 7;
  for (int e = slot; e < KSEL; e += 32) {
    int idx = li[e];
    int a = (int)((unsigned)idx / 3249u);
    int pp = idx - a * 3249;
    int y = (int)((unsigned)pp / 57u);
    int x = pp - y * 57;
    int dy = y - row0;
    if (dy < -7 || dy > 7) continue;
    double val = (double)lv[e];
    const float* wp = Wf + (a << 6) + kw;
#pragma unroll
    for (int kh = 0; kh < 8; ++kh) {
      int rr = dy + kh;
      if ((unsigned)rr < 8u)
        __hip_atomic_fetch_add(&accd[(rr << 6) + x + kw],
                               val * (double)wp[kh << 3],
                               __ATOMIC_RELAXED, __HIP_MEMORY_SCOPE_WORKGROUP);
    }
  }
  __syncthreads();
  const float* Yb = Y + (((size_t)(s * CCH + c)) << 12) + (row0 << 6);
  float* Rb = R + (((size_t)(s * CCH + c)) << 12) + (row0 << 6);
  for (int e = tid; e < 512; e += 256)
    Rb[e] = (float)(accd[e] - (double)Yb[e]);
}

// ---------------------------------------------------------------------------
// HT~ = Xprev - Dt(R) in f32 (classification only), fused L1 hist. r14
// verified, unchanged.
// ---------------------------------------------------------------------------
template <typename TR>
__global__ __launch_bounds__(256) void convDt_k(const TR* __restrict__ R,
    const float* __restrict__ Wt2f, const float* __restrict__ Xprev,
    float* __restrict__ HT, unsigned* __restrict__ g1) {
  __shared__ float Rl[3][15][72];
  __shared__ unsigned hh[1024];      // packed: 2 u16 bins per word
  int p = blockIdx.x;
  int lg = (p & 7) * 512 + (p >> 3);  // bijective: 4096 = 8*512
  int b = lg >> 7; int rem = lg & 127; int ag = rem >> 3; int by = rem & 7;
  int row0 = by * 8;
  int a0 = ag * 8;
  int tid = threadIdx.x;
  for (int e = tid; e < 1024; e += 256) hh[e] = 0;
  for (int e = tid; e < 3 * 15 * 72; e += 256) {
    int c = e / (15 * 72); int r2 = e - c * (15 * 72);
    int rr = r2 / 72; int cc = r2 - rr * 72;
    int gr = row0 + rr;
    float v = 0.0f;
    if (cc < OWW && gr < OHH)
      v = (float)R[((size_t)(b * CCH + c) << 12) + (gr << 6) + cc];
    Rl[c][rr][cc] = v;
  }
  __syncthreads();
  int x = tid & 63, yg = tid >> 6;
  int yb = yg * 2;
  float acc[8][2];
#pragma unroll
  for (int aa = 0; aa < 8; ++aa) { acc[aa][0] = 0.0f; acc[aa][1] = 0.0f; }

#pragma unroll 1
  for (int c = 0; c < 3; ++c) {
#pragma unroll 1
    for (int j = 0; j < 8; ++j) {
      float rw[9];
#pragma unroll
      for (int r = 0; r < 9; ++r) rw[r] = Rl[c][yb + r][x + j];
#pragma unroll
      for (int i = 0; i < 8; ++i) {
        const float* wp = Wt2f + ((c * 8 + i) * 8 + j) * 128 + a0;  // uniform
#pragma unroll
        for (int aa = 0; aa < 8; ++aa) {
          float w = wp[aa];
          acc[aa][0] = fmaf(rw[i + 0], w, acc[aa][0]);
          acc[aa][1] = fmaf(rw[i + 1], w, acc[aa][1]);
        }
      }
    }
  }
  if (x < XW) {
#pragma unroll
    for (int ty = 0; ty < 2; ++ty) {
      int yy = row0 + yb + ty;
      if (yy < XH) {
#pragma unroll
        for (int aa = 0; aa < 8; ++aa) {
          size_t xo = (size_t)(b * ATOMS + a0 + aa) * PIX + yy * XW + x;
          float fv = Xprev[xo] - acc[aa][ty];
          HT[xo] = fv;
          unsigned u = __float_as_uint(fv) & 0x7fffffffu;
          unsigned bin = u >> 20;
          atomicAdd(&hh[bin >> 1], 1u << ((bin & 1) << 4));
        }
      }
    }
  }
  __syncthreads();
  unsigned* gp = g1 + (size_t)b * 2048;
  for (int e = tid; e < 1024; e += 256) {
    unsigned v = hh[e];
    unsigned lo = v & 0xffffu, hi = v >> 16;
    if (lo) atomicAdd(&gp[2 * e], lo);
    if (hi) atomicAdd(&gp[2 * e + 1], hi);
  }
}

// ---------------------------------------------------------------------------
// histwrite_k: classify by approx bin with 1-bin safety band; stash the
// PREVIOUS X value for each candidate (read prevX before overwriting Xo —
// may alias, read-then-write per thread, so NO __restrict on Xo/prevX).
//   bin <  b1-1 -> certainly out: Xo = 0
//   bin >= b1-1 -> candidate: Xo placeholder; cand += i; candprev += prevX[i]
// ---------------------------------------------------------------------------
__global__ __launch_bounds__(256) void histwrite_k(const float* __restrict__ HT,
    const unsigned* __restrict__ g1, int* __restrict__ cand,
    int* __restrict__ candcnt, float* __restrict__ candprev,
    float* Xo, const float* prevX) {
  __shared__ unsigned part[256];
  __shared__ int lidx[4096];
  __shared__ float lprev[4096];
  __shared__ int lcnt, lbase, b1_sh;
  int tid = threadIdx.x;
  int s = blockIdx.x >> 5;
  int chunk = blockIdx.x & 31;
  const unsigned* hg1 = g1 + (size_t)s * 2048;
  unsigned psum = 0;
#pragma unroll
  for (int e = 0; e < 8; ++e) psum += hg1[tid * 8 + e];
  part[tid] = psum;
  if (tid == 0) lcnt = 0;
  __syncthreads();
  if (tid == 0) {
    int Kv = KSEL;
    unsigned cumBefore = 0;
    int bsel = 0;
    for (int q = 255; q >= 0; --q) {
      unsigned ps = part[q];
      if ((int)(cumBefore + ps) >= Kv) {
        for (int e = q * 8 + 7;; --e) {
          unsigned c2 = cumBefore + hg1[e];
          if ((int)c2 >= Kv) { bsel = e; break; }
          cumBefore = c2;
        }
        break;
      }
      cumBefore += ps;
    }
    b1_sh = bsel;
  }
  __syncthreads();
  unsigned blo = (unsigned)(b1_sh > 0 ? b1_sh - 1 : 0);
  size_t sbase = (size_t)s * NPS;
  const uint4* U4 = (const uint4*)(HT + sbase);
  const float4* P4 = (const float4*)(prevX + sbase);
  float4* X4 = (float4*)(Xo + sbase);
  for (int i4 = chunk * 256 + tid; i4 < NPS / 4; i4 += 32 * 256) {
    uint4 v = U4[i4];
    float4 pv = P4[i4];              // read BEFORE write (may alias Xo)
    unsigned uu[4] = {v.x, v.y, v.z, v.w};
    float pp[4] = {pv.x, pv.y, pv.z, pv.w};
    float oo[4];
#pragma unroll
    for (int t = 0; t < 4; ++t) {
      int il = i4 * 4 + t;
      unsigned u = uu[t] & 0x7fffffffu;
      unsigned bin = u >> 20;
      if (bin >= blo) {
        oo[t] = __uint_as_float(uu[t]);       // placeholder, pass3 overwrites
        int pos = atomicAdd(&lcnt, 1);
        if (pos < 4096) { lidx[pos] = il; lprev[pos] = pp[t]; }
      } else {
        oo[t] = 0.0f;
      }
    }
    X4[i4] = make_float4(oo[0], oo[1], oo[2], oo[3]);
  }
  __syncthreads();
  if (tid == 0) {
    int n = lcnt < 4096 ? lcnt : 4096;
    lbase = atomicAdd(&candcnt[s], n);
  }
  __syncthreads();
  int n = lcnt < 4096 ? lcnt : 4096;
  for (int e = tid; e < n; e += 256) {
    int g = lbase + e;
    if (g < CANDCAP) {
      cand[s * CANDCAP + g] = lidx[e];
      candprev[s * CANDCAP + g] = lprev[e];
    }
  }
}

// ---------------------------------------------------------------------------
// recompute_k: EXACT f64 re-evaluation of every candidate. xprev from
// candprev (no hash). Weights from Wcand: 192 CONTIGUOUS f32 per atom.
// grid = 32 samples x 32 chunks (4 blocks/CU).
// ---------------------------------------------------------------------------
template <typename TR>
__global__ __launch_bounds__(256) void recompute_k(const TR* __restrict__ R,
    const float* __restrict__ Wcand, const int* __restrict__ cand,
    const int* __restrict__ candcnt, const float* __restrict__ candprev,
    float* __restrict__ candval, unsigned* __restrict__ g1x) {
  __shared__ unsigned hx[2048];
  int s = blockIdx.x >> 5;
  int chunk = blockIdx.x & 31;
  int tid = threadIdx.x;
  for (int e = tid; e < 2048; e += 256) hx[e] = 0;
  __syncthreads();
  int n = candcnt[s];
  if (n > CANDCAP) n = CANDCAP;
  const TR* Rb = R + ((size_t)(s * 3) << 12);
  for (int e = chunk * 256 + tid; e < n; e += 32 * 256) {
    int i = cand[s * CANDCAP + e];
    int a = (int)((unsigned)i / 3249u);
    int p = i - a * 3249;
    int y = (int)((unsigned)p / 57u);
    int x = p - y * 57;
    double xprev = (double)candprev[s * CANDCAP + e];
    const float* wa = Wcand + (a << 8);
    double acc = 0.0;
    for (int c = 0; c < 3; ++c) {
#pragma unroll
      for (int ii = 0; ii < 8; ++ii) {
        const TR* rrow = Rb + (c << 12) + ((y + ii) << 6) + x;
        const float* wrow = wa + (c * 8 + ii) * 8;
#pragma unroll
        for (int jj = 0; jj < 8; ++jj)
          acc = fma((double)rrow[jj], (double)wrow[jj], acc);
      }
    }
    float cf = (float)(xprev - acc);
    candval[s * CANDCAP + e] = cf;
    unsigned u = __float_as_uint(cf) & 0x7fffffffu;
    atomicAdd(&hx[u >> 20], 1u);
  }
  __syncthreads();
  unsigned* gp = g1x + (size_t)s * 2048;
  for (int e = tid; e < 2048; e += 256)
    if (hx[e]) atomicAdd(&gp[e], hx[e]);
}

// ---------------------------------------------------------------------------
// pass3_k: exact 3-level radix select over candidates (recomputed values),
// tie resolution by lowest index, Xout fixup, nz-list emit, state reset.
// r14 verified, unchanged.
// ---------------------------------------------------------------------------
__global__ __launch_bounds__(256) void pass3_k(const int* __restrict__ cand,
    int* __restrict__ candcnt, const float* __restrict__ candval,
    unsigned* __restrict__ g1, unsigned* __restrict__ g1x,
    float* __restrict__ Xo, int* __restrict__ nzidx, float* __restrict__ nzval,
    int emit) {
  int s = blockIdx.x;
  __shared__ unsigned h[1024];
  __shared__ unsigned part[256];
  __shared__ int eqidx[1024];
  __shared__ int kidx[2048];
  __shared__ float kval[2048];
  __shared__ int eqn, kcnt;
  __shared__ unsigned tau_sh;
  __shared__ int k3_sh, cutoff_sh, b1_sh, k1_sh, b2_sh, k2_sh;
  int t = threadIdx.x;
  unsigned* hx = g1x + (size_t)s * 2048;
  unsigned s1 = 0;
#pragma unroll
  for (int e = 0; e < 8; ++e) s1 += hx[t * 8 + e];
  part[t] = s1;
  for (int e = t; e < 1024; e += 256) h[e] = 0;
  if (t == 0) { eqn = 0; kcnt = 0; }
  __syncthreads();
  if (t == 0) {
    int Kv = KSEL;
    unsigned cumBefore = 0;
    int bsel = 0;
    for (int q = 255; q >= 0; --q) {
      unsigned ps = part[q];
      if ((int)(cumBefore + ps) >= Kv) {
        for (int e = q * 8 + 7;; --e) {
          unsigned c2 = cumBefore + hx[e];
          if ((int)c2 >= Kv) { bsel = e; break; }
          cumBefore = c2;
        }
        break;
      }
      cumBefore += ps;
    }
    b1_sh = bsel;
    k1_sh = KSEL - (int)cumBefore;
  }
  __syncthreads();
  int n = candcnt[s];
  if (n > CANDCAP) n = CANDCAP;
  const int* cs = cand + s * CANDCAP;
  const float* cv = candval + s * CANDCAP;
  unsigned b1x = (unsigned)b1_sh;
  for (int e = t; e < n; e += 256) {
    unsigned u = __float_as_uint(cv[e]) & 0x7fffffffu;
    if ((u >> 20) == b1x) atomicAdd(&h[(u >> 10) & 1023], 1u);
  }
  __syncthreads();
  part[t] = h[t * 4] + h[t * 4 + 1] + h[t * 4 + 2] + h[t * 4 + 3];
  __syncthreads();
  if (t == 0) {
    int Kv = k1_sh;
    unsigned cumBefore = 0;
    int bsel = 0;
    for (int q = 255; q >= 0; --q) {
      unsigned ps = part[q];
      if ((int)(cumBefore + ps) >= Kv) {
        for (int e = q * 4 + 3;; --e) {
          unsigned c2 = cumBefore + h[e];
          if ((int)c2 >= Kv) { bsel = e; break; }
          cumBefore = c2;
        }
        break;
      }
      cumBefore += ps;
    }
    b2_sh = bsel;
    k2_sh = Kv - (int)cumBefore;
  }
  __syncthreads();
  for (int e = t; e < 1024; e += 256) h[e] = 0;
  __syncthreads();
  unsigned pre21 = (b1x << 10) | (unsigned)b2_sh;
  for (int e = t; e < n; e += 256) {
    unsigned u = __float_as_uint(cv[e]) & 0x7fffffffu;
    if ((u >> 10) == pre21) atomicAdd(&h[u & 1023], 1u);
  }
  __syncthreads();
  if (t == 0) {
    int Kv = k2_sh;
    unsigned cumBefore = 0;
    int b3 = 0;
    for (int e = 1023; e >= 0; --e) {
      unsigned c2 = cumBefore + h[e];
      if ((int)c2 >= Kv) { b3 = e; break; }
      cumBefore = c2;
    }
    tau_sh = (pre21 << 10) | (unsigned)b3;
    k3_sh = Kv - (int)cumBefore;
  }
  __syncthreads();
  unsigned tau = tau_sh;
  for (int e = t; e < n; e += 256) {
    unsigned u = __float_as_uint(cv[e]) & 0x7fffffffu;
    if (u == tau) {
      int pos = atomicAdd(&eqn, 1);
      if (pos < 1024) eqidx[pos] = cs[e];
    }
  }
  __syncthreads();
  if (t == 0) {
    int m = eqn < 1024 ? eqn : 1024;
    int k3 = k3_sh;
    int cutoff;
    if (k3 >= m) {
      cutoff = 0x7fffffff;
    } else {
      int last = -1;
      for (int r = 0; r < k3; ++r) {
        int mn = 0x7fffffff;
        for (int q = 0; q < m; ++q) {
          int v = eqidx[q];
          if (v > last && v < mn) mn = v;
        }
        last = mn;
      }
      cutoff = last;
    }
    cutoff_sh = cutoff;
  }
  __syncthreads();
  int co = cutoff_sh;
  float* Xs = Xo + (size_t)s * NPS;
  for (int e = t; e < n; e += 256) {
    int i = cs[e];
    float cf = cv[e];
    unsigned u = __float_as_uint(cf) & 0x7fffffffu;
    bool keep = (u > tau) || (u == tau && i <= co);
    Xs[i] = keep ? cf : 0.0f;
    if (keep && emit) {
      int pos = atomicAdd(&kcnt, 1);
      if (pos < 2048) { kidx[pos] = i; kval[pos] = cf; }
    }
  }
  __syncthreads();
  if (emit) {
    int kn = kcnt < KSEL ? kcnt : KSEL;
    for (int e = t; e < kn; e += 256) {
      nzidx[s * KSEL + e] = kidx[e];
      nzval[s * KSEL + e] = kval[e];
    }
  }
  unsigned* hg1 = g1 + (size_t)s * 2048;
  for (int e = t; e < 2048; e += 256) { hg1[e] = 0; hx[e] = 0; }
  if (t == 0) candcnt[s] = 0;
}

extern "C" void kernel_launch(void* const* d_in, const int* in_sizes, int n_in,
                              void* d_out, int out_size, void* d_ws, size_t ws_size,
                              hipStream_t stream) {
  const float* Y  = (const float*)d_in[0];
  const float* X0 = (const float*)d_in[1];
  const float* Wg = (const float*)d_in[2];
  float* Xout = (float*)d_out;

  double* WDd  = (double*)d_ws;                        // NW f64
  float* Wt2f  = (float*)(WDd + NW);                   // NW f32
  float* Wcand = Wt2f + NW;                            // NWC f32
  float* HT   = Wcand + NWC;                           // NTOT f32
  float* Rbuf = HT + NTOT;                             // RTOT f32
  double* Rd  = (double*)(Rbuf + RTOT);                // RTOT f64
  unsigned* g1 = (unsigned*)(Rd + RTOT);               // 32*2048
  unsigned* g1x = g1 + 32 * 2048;                      // 32*2048
  int* candcnt = (int*)(g1x + 32 * 2048);              // 32
  int* cand = candcnt + 32;                            // 32*CANDCAP
  float* candval = (float*)(cand + 32 * CANDCAP);      // 32*CANDCAP
  float* candprev = candval + 32 * CANDCAP;            // 32*CANDCAP
  int* nzidx = (int*)(candprev + 32 * CANDCAP);        // 32*KSEL
  float* nzval = (float*)(nzidx + 32 * KSEL);          // 32*KSEL

  prep_k<<<dim3((RTOT + 255) / 256), dim3(256), 0, stream>>>(
      Wg, WDd, Wt2f, Wcand, Y, Rd, g1);

  for (int it = 0; it < 3; ++it) {
    if (it == 0) {
      convD_k<<<dim3(2048), dim3(256), 0, stream>>>(X0, WDd, Rd);
      convDt_k<double><<<dim3(4096), dim3(256), 0, stream>>>(Rd, Wt2f, X0, HT, g1);
    } else {
      convD_sparse_k<<<dim3(BATCH * CCH * 8), dim3(256), 0, stream>>>(
          Wg, nzidx, nzval, Y, Rbuf);
      convDt_k<float><<<dim3(4096), dim3(256), 0, stream>>>(Rbuf, Wt2f,
          (const float*)Xout, HT, g1);
    }
    histwrite_k<<<dim3(BATCH * 32), dim3(256), 0, stream>>>(
        HT, g1, cand, candcnt, candprev, Xout, (it == 0) ? X0 : (const float*)Xout);
    if (it == 0) {
      recompute_k<double><<<dim3(BATCH * 32), dim3(256), 0, stream>>>(
          Rd, Wcand, cand, candcnt, candprev, candval, g1x);
    } else {
      recompute_k<float><<<dim3(BATCH * 32), dim3(256), 0, stream>>>(
          Rbuf, Wcand, cand, candcnt, candprev, candval, g1x);
    }
    int emit = (it < 2) ? 1 : 0;
    pass3_k<<<dim3(BATCH), dim3(256), 0, stream>>>(
        cand, candcnt, candval, g1, g1x, Xout, nzidx, nzval, emit);
  }
}

// Round 16
// 942.396 us; speedup vs baseline: 1.4177x; 1.0136x over previous
//
#include <hip/hip_runtime.h>

#define BATCH 32
#define ATOMS 128
#define CCH 3
#define XH 57
#define XW 57
#define OHH 64
#define OWW 64
#define KSEL 2000
#define PIX (XH*XW)            // 3249
#define NPS (ATOMS*PIX)        // 415872 per-sample X elements
#define NTOT (BATCH*NPS)       // 13307904
#define RPS (CCH*OHH*OWW)      // 12288 per-sample R elements
#define RTOT (BATCH*RPS)       // 393216
#define CANDCAP 32768
#define NW 24576               // weight elements 128*3*8*8
#define NWC 32768              // Wcand padded: 128 atoms x 256
#define LCAP 6144              // per-block candidate cap
#define ZWORDS (32*2048 + 32)  // g1 + candcnt

// ---------------------------------------------------------------------------
// Prep (once): WDd f64 (convD), Wt2f f32 (convDt), Wcand f32 (exact dot,
// 192 contiguous per atom), Rd = -Y, zero g1/candcnt.
// ---------------------------------------------------------------------------
__global__ __launch_bounds__(256) void prep_k(const float* __restrict__ Wg,
    double* __restrict__ WDd, float* __restrict__ Wt2f,
    float* __restrict__ Wcand, const float* __restrict__ Y,
    double* __restrict__ Rd, unsigned* __restrict__ zbuf) {
  int e = blockIdx.x * 256 + threadIdx.x;
  if (e < NW) {
    {
      int kw = e & 7; int t = e >> 3; int c = t % 3; t /= 3; int kh = t & 7; int a = t >> 3;
      WDd[e] = (double)Wg[(a*3 + c)*64 + kh*8 + kw];
    }
    {
      int a = e & 127; int t = e >> 7; int j = t & 7; int i = (t >> 3) & 7; int c = t >> 6;
      Wt2f[e] = Wg[(a*3 + c)*64 + j*8 + i];   // [c][i][j][a], exact f32
    }
  }
  if (e < NWC) {
    int a = e >> 8, r = e & 255;
    float v = 0.0f;
    if (r < 192) {
      int c = r >> 6, ii = (r >> 3) & 7, jj = r & 7;
      v = Wg[(a*3 + c)*64 + jj*8 + ii];       // Wcand[a][(c*8+ii)*8+jj]=W[a,c,jj,ii]
    }
    Wcand[e] = v;
  }
  if (e < RTOT) Rd[e] = -(double)Y[e];
  if (e < ZWORDS) zbuf[e] = 0;
}

// ---------------------------------------------------------------------------
// DENSE R += D(X) (iteration 0 only). Verified r11/r12 version, unchanged.
// ---------------------------------------------------------------------------
__global__ __launch_bounds__(256) void convD_k(const float* __restrict__ X,
    const double* __restrict__ WDd, double* __restrict__ Rd) {
  __shared__ double Xs[4][11][72];            // 25344 B
  int p = blockIdx.x;
  int lg = (p & 7) * 256 + (p >> 3);          // bijective: 2048 = 8*256
  int b = lg >> 6; int rem = lg & 63;
  int band = rem >> 2, quarter = rem & 3;
  int row0 = band * 4;
  int a_base = quarter * 32;
  int tid = threadIdx.x;
  int ox = tid & 63;
  int wv = __builtin_amdgcn_readfirstlane(tid >> 6);
  const float* Xb = X + (size_t)b * NPS;

  double acc[4][3];
#pragma unroll
  for (int ty = 0; ty < 4; ++ty)
#pragma unroll
    for (int c = 0; c < 3; ++c) acc[ty][c] = 0.0;

  for (int ch = 0; ch < 8; ++ch) {
    __syncthreads();
    for (int e = tid; e < 4 * 11 * 72; e += 256) {
      int ai = e / 792; int rem2 = e - ai * 792;
      int r = rem2 / 72; int ss = rem2 - r * 72;
      int gy = row0 - 7 + r;
      int xcol = ss - 7;
      int a = a_base + ch * 4 + ai;
      float v = 0.0f;
      if ((unsigned)xcol < (unsigned)XW && (unsigned)gy < (unsigned)XH)
        v = Xb[a * PIX + gy * XW + xcol];
      Xs[ai][r][ss] = (double)v;
    }
    __syncthreads();
    {
      int a = a_base + ch * 4 + wv;
      const double* Wa = WDd + a * 192;       // [kh][c][kw]
#pragma unroll
      for (int r = 0; r < 11; ++r) {
        int gy = row0 - 7 + r;
        if ((unsigned)gy >= (unsigned)XH) continue;   // uniform
        double xd[8];
#pragma unroll
        for (int t = 0; t < 8; ++t) xd[t] = Xs[wv][r][ox + t];
#pragma unroll
        for (int ty = 0; ty < 4; ++ty) {
          int kh = ty + 7 - r;
          if ((unsigned)kh < 8u) {
            const double* Wk = Wa + kh * 24;
#pragma unroll
            for (int kw = 0; kw < 8; ++kw) {
              acc[ty][0] = fma(xd[7 - kw], Wk[kw],      acc[ty][0]);
              acc[ty][1] = fma(xd[7 - kw], Wk[8 + kw],  acc[ty][1]);
              acc[ty][2] = fma(xd[7 - kw], Wk[16 + kw], acc[ty][2]);
            }
          }
        }
      }
    }
  }
#pragma unroll
  for (int ty = 0; ty < 4; ++ty) {
    int oy = row0 + ty;
#pragma unroll
    for (int c = 0; c < 3; ++c)
      atomicAdd(&Rd[((size_t)(b * CCH + c) << 12) + (oy << 6) + ox], acc[ty][c]);
  }
}

// ---------------------------------------------------------------------------
// SPARSE R = D(X) - Y (iterations 1,2). Verified, unchanged.
// ---------------------------------------------------------------------------
__global__ __launch_bounds__(256) void convD_sparse_k(const float* __restrict__ Wg,
    const int* __restrict__ nzidx, const float* __restrict__ nzval,
    const float* __restrict__ Y, float* __restrict__ R) {
  __shared__ double accd[512];       // [rr][ox]
  __shared__ float Wf[8192];         // [a][kh][kw] for this c
  __shared__ int   li[KSEL];
  __shared__ float lv[KSEL];
  int p = blockIdx.x;
  int lg = (p & 7) * 96 + (p >> 3);  // bijective: 768 = 8*96
  int s = lg / 24; int r = lg % 24; int c = r >> 3; int band = r & 7;
  int row0 = band * 8;
  int tid = threadIdx.x;
  for (int e = tid; e < 512; e += 256) accd[e] = 0.0;
  for (int e = tid; e < 8192; e += 256) {
    int a = e >> 6, k2 = e & 63;
    Wf[e] = Wg[(a * 3 + c) * 64 + k2];
  }
  for (int e = tid; e < KSEL; e += 256) {
    li[e] = nzidx[s * KSEL + e];
    lv[e] = nzval[s * KSEL + e];
  }
  __syncthreads();
  int slot = tid >> 3, kw = tid & 7;
  for (int e = slot; e < KSEL; e += 32) {
    int idx = li[e];
    int a = (int)((unsigned)idx / 3249u);
    int pp = idx - a * 3249;
    int y = (int)((unsigned)pp / 57u);
    int x = pp - y * 57;
    int dy = y - row0;
    if (dy < -7 || dy > 7) continue;
    double val = (double)lv[e];
    const float* wp = Wf + (a << 6) + kw;
#pragma unroll
    for (int kh = 0; kh < 8; ++kh) {
      int rr = dy + kh;
      if ((unsigned)rr < 8u)
        __hip_atomic_fetch_add(&accd[(rr << 6) + x + kw],
                               val * (double)wp[kh << 3],
                               __ATOMIC_RELAXED, __HIP_MEMORY_SCOPE_WORKGROUP);
    }
  }
  __syncthreads();
  const float* Yb = Y + (((size_t)(s * CCH + c)) << 12) + (row0 << 6);
  float* Rb = R + (((size_t)(s * CCH + c)) << 12) + (row0 << 6);
  for (int e = tid; e < 512; e += 256)
    Rb[e] = (float)(accd[e] - (double)Yb[e]);
}

// ---------------------------------------------------------------------------
// HT~ = Xprev - Dt(R) in f32 (classification only), fused L1 hist.
// r14/r15 verified, unchanged.
// ---------------------------------------------------------------------------
template <typename TR>
__global__ __launch_bounds__(256) void convDt_k(const TR* __restrict__ R,
    const float* __restrict__ Wt2f, const float* __restrict__ Xprev,
    float* __restrict__ HT, unsigned* __restrict__ g1) {
  __shared__ float Rl[3][15][72];
  __shared__ unsigned hh[1024];      // packed: 2 u16 bins per word
  int p = blockIdx.x;
  int lg = (p & 7) * 512 + (p >> 3);  // bijective: 4096 = 8*512
  int b = lg >> 7; int rem = lg & 127; int ag = rem >> 3; int by = rem & 7;
  int row0 = by * 8;
  int a0 = ag * 8;
  int tid = threadIdx.x;
  for (int e = tid; e < 1024; e += 256) hh[e] = 0;
  for (int e = tid; e < 3 * 15 * 72; e += 256) {
    int c = e / (15 * 72); int r2 = e - c * (15 * 72);
    int rr = r2 / 72; int cc = r2 - rr * 72;
    int gr = row0 + rr;
    float v = 0.0f;
    if (cc < OWW && gr < OHH)
      v = (float)R[((size_t)(b * CCH + c) << 12) + (gr << 6) + cc];
    Rl[c][rr][cc] = v;
  }
  __syncthreads();
  int x = tid & 63, yg = tid >> 6;
  int yb = yg * 2;
  float acc[8][2];
#pragma unroll
  for (int aa = 0; aa < 8; ++aa) { acc[aa][0] = 0.0f; acc[aa][1] = 0.0f; }

#pragma unroll 1
  for (int c = 0; c < 3; ++c) {
#pragma unroll 1
    for (int j = 0; j < 8; ++j) {
      float rw[9];
#pragma unroll
      for (int r = 0; r < 9; ++r) rw[r] = Rl[c][yb + r][x + j];
#pragma unroll
      for (int i = 0; i < 8; ++i) {
        const float* wp = Wt2f + ((c * 8 + i) * 8 + j) * 128 + a0;  // uniform
#pragma unroll
        for (int aa = 0; aa < 8; ++aa) {
          float w = wp[aa];
          acc[aa][0] = fmaf(rw[i + 0], w, acc[aa][0]);
          acc[aa][1] = fmaf(rw[i + 1], w, acc[aa][1]);
        }
      }
    }
  }
  if (x < XW) {
#pragma unroll
    for (int ty = 0; ty < 2; ++ty) {
      int yy = row0 + yb + ty;
      if (yy < XH) {
#pragma unroll
        for (int aa = 0; aa < 8; ++aa) {
          size_t xo = (size_t)(b * ATOMS + a0 + aa) * PIX + yy * XW + x;
          float fv = Xprev[xo] - acc[aa][ty];
          HT[xo] = fv;
          unsigned u = __float_as_uint(fv) & 0x7fffffffu;
          unsigned bin = u >> 20;
          atomicAdd(&hh[bin >> 1], 1u << ((bin & 1) << 4));
        }
      }
    }
  }
  __syncthreads();
  unsigned* gp = g1 + (size_t)b * 2048;
  for (int e = tid; e < 1024; e += 256) {
    unsigned v = hh[e];
    unsigned lo = v & 0xffffu, hi = v >> 16;
    if (lo) atomicAdd(&gp[2 * e], lo);
    if (hi) atomicAdd(&gp[2 * e + 1], hi);
  }
}

// ---------------------------------------------------------------------------
// histwrite_k (recompute fused): classify with 2-bin safety band.
//   approx bin <  b1-2 -> certainly out: write 0
//   approx bin >= b1-2 -> candidate: SKIP the store (at it>=1 Xo[i] still
//     holds prev X; pass3 writes every candidate), append to cand, then
//     EXACT f64 re-eval: candval = Xp[i] - sum_k R[k-nb]*W (Wcand contiguous).
// Xp = X0 (it0) or Xo itself (it>=1); each block only touches its own chunk.
// ---------------------------------------------------------------------------
template <typename TR>
__global__ __launch_bounds__(256) void histwrite_k(const float* __restrict__ HT,
    const unsigned* __restrict__ g1, const TR* __restrict__ R,
    const float* __restrict__ Wcand, const float* Xp,
    int* __restrict__ cand, int* __restrict__ candcnt,
    float* __restrict__ candval, float* Xo) {
  __shared__ unsigned part[256];
  __shared__ int lidx[LCAP];
  __shared__ int lcnt, lbase, b1_sh;
  int tid = threadIdx.x;
  int s = blockIdx.x >> 5;
  int chunk = blockIdx.x & 31;
  const unsigned* hg1 = g1 + (size_t)s * 2048;
  unsigned psum = 0;
#pragma unroll
  for (int e = 0; e < 8; ++e) psum += hg1[tid * 8 + e];
  part[tid] = psum;
  if (tid == 0) lcnt = 0;
  __syncthreads();
  if (tid == 0) {
    int Kv = KSEL;
    unsigned cumBefore = 0;
    int bsel = 0;
    for (int q = 255; q >= 0; --q) {
      unsigned ps = part[q];
      if ((int)(cumBefore + ps) >= Kv) {
        for (int e = q * 8 + 7;; --e) {
          unsigned c2 = cumBefore + hg1[e];
          if ((int)c2 >= Kv) { bsel = e; break; }
          cumBefore = c2;
        }
        break;
      }
      cumBefore += ps;
    }
    b1_sh = bsel;
  }
  __syncthreads();
  unsigned blo = (unsigned)(b1_sh >= 2 ? b1_sh - 2 : 0);
  size_t sbase = (size_t)s * NPS;
  const uint4* U4 = (const uint4*)(HT + sbase);
  float4* X4 = (float4*)(Xo + sbase);
  for (int i4 = chunk * 256 + tid; i4 < NPS / 4; i4 += 32 * 256) {
    uint4 v = U4[i4];
    unsigned uu[4] = {v.x, v.y, v.z, v.w};
    int m = 0;
#pragma unroll
    for (int t = 0; t < 4; ++t) {
      unsigned u = uu[t] & 0x7fffffffu;
      if ((u >> 20) >= blo) {
        m |= 1 << t;
        int pos = atomicAdd(&lcnt, 1);
        if (pos < LCAP) lidx[pos] = i4 * 4 + t;
      }
    }
    if (m == 0) {
      X4[i4] = make_float4(0.0f, 0.0f, 0.0f, 0.0f);
    } else {
#pragma unroll
      for (int t = 0; t < 4; ++t)
        if (!(m & (1 << t))) Xo[sbase + i4 * 4 + t] = 0.0f;
    }
  }
  __syncthreads();
  if (tid == 0) {
    int nn = lcnt < LCAP ? lcnt : LCAP;
    lbase = atomicAdd(&candcnt[s], nn);
  }
  __syncthreads();
  int nn = lcnt < LCAP ? lcnt : LCAP;
  // exact f64 re-evaluation of this block's candidates
  const TR* Rb = R + ((size_t)(s * 3) << 12);
  for (int e = tid; e < nn; e += 256) {
    int i = lidx[e];
    int g = lbase + e;
    int a = (int)((unsigned)i / 3249u);
    int p = i - a * 3249;
    int y = (int)((unsigned)p / 57u);
    int x = p - y * 57;
    double xprev = (double)Xp[sbase + i];     // candidate lane: never zeroed
    const float* wa = Wcand + (a << 8);
    double acc = 0.0;
    for (int c = 0; c < 3; ++c) {
#pragma unroll
      for (int ii = 0; ii < 8; ++ii) {
        const TR* rrow = Rb + (c << 12) + ((y + ii) << 6) + x;
        const float* wrow = wa + (c * 8 + ii) * 8;
#pragma unroll
        for (int jj = 0; jj < 8; ++jj)
          acc = fma((double)rrow[jj], (double)wrow[jj], acc);
      }
    }
    float cf = (float)(xprev - acc);
    if (g < CANDCAP) {
      cand[s * CANDCAP + g] = i;
      candval[s * CANDCAP + g] = cf;
    }
  }
}

// ---------------------------------------------------------------------------
// pass3_k: exact 3-level radix select over candidate values (self-computed
// L1 hist), tie resolution by lowest index, Xout fixup (every candidate),
// nz-list emit, per-sample g1/candcnt reset. One block per sample.
// ---------------------------------------------------------------------------
__global__ __launch_bounds__(256) void pass3_k(const int* __restrict__ cand,
    int* __restrict__ candcnt, const float* __restrict__ candval,
    unsigned* __restrict__ g1, float* __restrict__ Xo,
    int* __restrict__ nzidx, float* __restrict__ nzval, int emit) {
  int s = blockIdx.x;
  __shared__ unsigned h[2048];
  __shared__ unsigned part[256];
  __shared__ int eqidx[1024];
  __shared__ int kidx[2048];
  __shared__ float kval[2048];
  __shared__ int eqn, kcnt;
  __shared__ unsigned tau_sh;
  __shared__ int k3_sh, cutoff_sh, b1_sh, k1_sh, b2_sh, k2_sh;
  int t = threadIdx.x;
  int n = candcnt[s];
  if (n > CANDCAP) n = CANDCAP;
  const int* cs = cand + s * CANDCAP;
  const float* cv = candval + s * CANDCAP;
  for (int e = t; e < 2048; e += 256) h[e] = 0;
  if (t == 0) { eqn = 0; kcnt = 0; }
  __syncthreads();
  // ---- level 1 over candidates ----
  for (int e = t; e < n; e += 256) {
    unsigned u = __float_as_uint(cv[e]) & 0x7fffffffu;
    atomicAdd(&h[u >> 20], 1u);
  }
  __syncthreads();
  unsigned s1 = 0;
#pragma unroll
  for (int e = 0; e < 8; ++e) s1 += h[t * 8 + e];
  part[t] = s1;
  __syncthreads();
  if (t == 0) {
    int Kv = KSEL;
    unsigned cumBefore = 0;
    int bsel = 0;
    for (int q = 255; q >= 0; --q) {
      unsigned ps = part[q];
      if ((int)(cumBefore + ps) >= Kv) {
        for (int e = q * 8 + 7;; --e) {
          unsigned c2 = cumBefore + h[e];
          if ((int)c2 >= Kv) { bsel = e; break; }
          cumBefore = c2;
        }
        break;
      }
      cumBefore += ps;
    }
    b1_sh = bsel;
    k1_sh = KSEL - (int)cumBefore;
  }
  __syncthreads();
  unsigned b1x = (unsigned)b1_sh;
  for (int e = t; e < 1024; e += 256) h[e] = 0;
  __syncthreads();
  // ---- level 2 ----
  for (int e = t; e < n; e += 256) {
    unsigned u = __float_as_uint(cv[e]) & 0x7fffffffu;
    if ((u >> 20) == b1x) atomicAdd(&h[(u >> 10) & 1023], 1u);
  }
  __syncthreads();
  part[t] = h[t * 4] + h[t * 4 + 1] + h[t * 4 + 2] + h[t * 4 + 3];
  __syncthreads();
  if (t == 0) {
    int Kv = k1_sh;
    unsigned cumBefore = 0;
    int bsel = 0;
    for (int q = 255; q >= 0; --q) {
      unsigned ps = part[q];
      if ((int)(cumBefore + ps) >= Kv) {
        for (int e = q * 4 + 3;; --e) {
          unsigned c2 = cumBefore + h[e];
          if ((int)c2 >= Kv) { bsel = e; break; }
          cumBefore = c2;
        }
        break;
      }
      cumBefore += ps;
    }
    b2_sh = bsel;
    k2_sh = Kv - (int)cumBefore;
  }
  __syncthreads();
  for (int e = t; e < 1024; e += 256) h[e] = 0;
  __syncthreads();
  // ---- level 3 ----
  unsigned pre21 = (b1x << 10) | (unsigned)b2_sh;
  for (int e = t; e < n; e += 256) {
    unsigned u = __float_as_uint(cv[e]) & 0x7fffffffu;
    if ((u >> 10) == pre21) atomicAdd(&h[u & 1023], 1u);
  }
  __syncthreads();
  if (t == 0) {
    int Kv = k2_sh;
    unsigned cumBefore = 0;
    int b3 = 0;
    for (int e = 1023; e >= 0; --e) {
      unsigned c2 = cumBefore + h[e];
      if ((int)c2 >= Kv) { b3 = e; break; }
      cumBefore = c2;
    }
    tau_sh = (pre21 << 10) | (unsigned)b3;
    k3_sh = Kv - (int)cumBefore;
  }
  __syncthreads();
  unsigned tau = tau_sh;
  for (int e = t; e < n; e += 256) {
    unsigned u = __float_as_uint(cv[e]) & 0x7fffffffu;
    if (u == tau) {
      int pos = atomicAdd(&eqn, 1);
      if (pos < 1024) eqidx[pos] = cs[e];
    }
  }
  __syncthreads();
  if (t == 0) {
    int m = eqn < 1024 ? eqn : 1024;
    int k3 = k3_sh;
    int cutoff;
    if (k3 >= m) {
      cutoff = 0x7fffffff;
    } else {
      int last = -1;
      for (int r = 0; r < k3; ++r) {
        int mn = 0x7fffffff;
        for (int q = 0; q < m; ++q) {
          int v = eqidx[q];
          if (v > last && v < mn) mn = v;
        }
        last = mn;
      }
      cutoff = last;
    }
    cutoff_sh = cutoff;
  }
  __syncthreads();
  // ---- fixup: write EVERY candidate position in Xout ----
  int co = cutoff_sh;
  float* Xs = Xo + (size_t)s * NPS;
  for (int e = t; e < n; e += 256) {
    int i = cs[e];
    float cf = cv[e];
    unsigned u = __float_as_uint(cf) & 0x7fffffffu;
    bool keep = (u > tau) || (u == tau && i <= co);
    Xs[i] = keep ? cf : 0.0f;
    if (keep && emit) {
      int pos = atomicAdd(&kcnt, 1);
      if (pos < 2048) { kidx[pos] = i; kval[pos] = cf; }
    }
  }
  __syncthreads();
  if (emit) {
    int kn = kcnt < KSEL ? kcnt : KSEL;
    for (int e = t; e < kn; e += 256) {
      nzidx[s * KSEL + e] = kidx[e];
      nzval[s * KSEL + e] = kval[e];
    }
  }
  // reset per-sample state for next iteration
  unsigned* hg1 = g1 + (size_t)s * 2048;
  for (int e = t; e < 2048; e += 256) hg1[e] = 0;
  if (t == 0) candcnt[s] = 0;
}

extern "C" void kernel_launch(void* const* d_in, const int* in_sizes, int n_in,
                              void* d_out, int out_size, void* d_ws, size_t ws_size,
                              hipStream_t stream) {
  const float* Y  = (const float*)d_in[0];
  const float* X0 = (const float*)d_in[1];
  const float* Wg = (const float*)d_in[2];
  float* Xout = (float*)d_out;

  double* WDd  = (double*)d_ws;                        // NW f64
  float* Wt2f  = (float*)(WDd + NW);                   // NW f32
  float* Wcand = Wt2f + NW;                            // NWC f32
  float* HT   = Wcand + NWC;                           // NTOT f32
  float* Rbuf = HT + NTOT;                             // RTOT f32
  double* Rd  = (double*)(Rbuf + RTOT);                // RTOT f64
  unsigned* g1 = (unsigned*)(Rd + RTOT);               // 32*2048
  int* candcnt = (int*)(g1 + 32 * 2048);               // 32
  int* cand = candcnt + 32;                            // 32*CANDCAP
  float* candval = (float*)(cand + 32 * CANDCAP);      // 32*CANDCAP
  int* nzidx = (int*)(candval + 32 * CANDCAP);         // 32*KSEL
  float* nzval = (float*)(nzidx + 32 * KSEL);          // 32*KSEL

  prep_k<<<dim3((RTOT + 255) / 256), dim3(256), 0, stream>>>(
      Wg, WDd, Wt2f, Wcand, Y, Rd, g1);

  for (int it = 0; it < 3; ++it) {
    if (it == 0) {
      convD_k<<<dim3(2048), dim3(256), 0, stream>>>(X0, WDd, Rd);
      convDt_k<double><<<dim3(4096), dim3(256), 0, stream>>>(Rd, Wt2f, X0, HT, g1);
      histwrite_k<double><<<dim3(BATCH * 32), dim3(256), 0, stream>>>(
          HT, g1, Rd, Wcand, X0, cand, candcnt, candval, Xout);
    } else {
      convD_sparse_k<<<dim3(BATCH * CCH * 8), dim3(256), 0, stream>>>(
          Wg, nzidx, nzval, Y, Rbuf);
      convDt_k<float><<<dim3(4096), dim3(256), 0, stream>>>(Rbuf, Wt2f,
          (const float*)Xout, HT, g1);
      histwrite_k<float><<<dim3(BATCH * 32), dim3(256), 0, stream>>>(
          HT, g1, Rbuf, Wcand, (const float*)Xout, cand, candcnt, candval, Xout);
    }
    int emit = (it < 2) ? 1 : 0;
    pass3_k<<<dim3(BATCH), dim3(256), 0, stream>>>(
        cand, candcnt, candval, g1, Xout, nzidx, nzval, emit);
  }
}